// Round 1
// baseline (6794.717 us; speedup 1.0000x reference)
//
#include <hip/hip_runtime.h>
#include <cstdint>
#include <cstddef>

#define T4096 4096
#define TM1 4095
#define NV 88
#define NH 512
#define NR 512
#define GS 20
#define EPSV 1e-6f

// ws float offsets
#define U_OFF 0                         // 4095*512 floats
#define AB_OFF 2096640                  // A, later aliased by bh_t (4095*512)
#define BV_OFF 4193280                  // bv_t 4095*88
#define SC_OFF 4553640                  // scalars + sync area (see layout below)
// u32 layout at sc: [0..2] accumulators, [8..15] xcd claim counts,
// [16] winner, [17..48] handshake words (4 rounds x 8 slots), [49..56] verdicts

__device__ __forceinline__ unsigned int agent_load_u32(const unsigned int* p) {
  return __hip_atomic_load(p, __ATOMIC_RELAXED, __HIP_MEMORY_SCOPE_AGENT);
}
__device__ __forceinline__ void agent_store_f32(float* p, float v) {
  __hip_atomic_store(p, v, __ATOMIC_RELAXED, __HIP_MEMORY_SCOPE_AGENT);
}
__device__ __forceinline__ float sigmoidf_(float x) {
  return 1.0f / (1.0f + expf(-x));
}

// sc0 = SE-scope: bypasses L1, served by the XCD-shared L2.
__device__ __forceinline__ void store_sc0(float* p, float v) {
  asm volatile("global_store_dword %0, %1, off sc0" :: "v"(p), "v"(v) : "memory");
}
__device__ __forceinline__ unsigned load_sc0(const unsigned* p) {
  unsigned r;
  asm volatile("global_load_dword %0, %1, off sc0\n\ts_waitcnt vmcnt(0)"
               : "=v"(r) : "v"(p) : "memory");
  return r;
}

// Staggered poll: 4 in-flight loads spaced ~64cyc; values are write-once
// (poison 0xFFFFFFFF -> tanh output), so any non-poison hit is THE value.
// Loops at wave level until every lane has a value.
__device__ __forceinline__ unsigned poll_stag_sc0(const unsigned* p) {
  unsigned r0, r1, r2, r3;
  asm volatile(
    "Lp%=:\n\t"
    "global_load_dword %0, %4, off sc0\n\t"
    "s_sleep 1\n\t"
    "global_load_dword %1, %4, off sc0\n\t"
    "s_sleep 1\n\t"
    "global_load_dword %2, %4, off sc0\n\t"
    "s_sleep 1\n\t"
    "global_load_dword %3, %4, off sc0\n\t"
    "s_waitcnt vmcnt(0)\n\t"
    "v_cmp_ne_u32 vcc, -1, %0\n\t"
    "v_cndmask_b32 %3, %3, %0, vcc\n\t"
    "v_cmp_ne_u32 vcc, -1, %1\n\t"
    "v_cndmask_b32 %3, %3, %1, vcc\n\t"
    "v_cmp_ne_u32 vcc, -1, %2\n\t"
    "v_cndmask_b32 %3, %3, %2, vcc\n\t"
    "v_cmp_eq_u32 vcc, -1, %3\n\t"
    "s_cbranch_vccnz Lp%=\n\t"
    : "=&v"(r0), "=&v"(r1), "=&v"(r2), "=&v"(r3)
    : "v"(p) : "vcc", "memory");
  return r3;
}
// System-scope variant (sc0 sc1): strongest coherence, always correct.
__device__ __forceinline__ unsigned poll_stag_sys(const unsigned* p) {
  unsigned r0, r1, r2, r3;
  asm volatile(
    "Lq%=:\n\t"
    "global_load_dword %0, %4, off sc0 sc1\n\t"
    "s_sleep 1\n\t"
    "global_load_dword %1, %4, off sc0 sc1\n\t"
    "s_sleep 1\n\t"
    "global_load_dword %2, %4, off sc0 sc1\n\t"
    "s_sleep 1\n\t"
    "global_load_dword %3, %4, off sc0 sc1\n\t"
    "s_waitcnt vmcnt(0)\n\t"
    "v_cmp_ne_u32 vcc, -1, %0\n\t"
    "v_cndmask_b32 %3, %3, %0, vcc\n\t"
    "v_cmp_ne_u32 vcc, -1, %1\n\t"
    "v_cndmask_b32 %3, %3, %1, vcc\n\t"
    "v_cmp_ne_u32 vcc, -1, %2\n\t"
    "v_cndmask_b32 %3, %3, %2, vcc\n\t"
    "v_cmp_eq_u32 vcc, -1, %3\n\t"
    "s_cbranch_vccnz Lq%=\n\t"
    : "=&v"(r0), "=&v"(r1), "=&v"(r2), "=&v"(r3)
    : "v"(p) : "vcc", "memory");
  return r3;
}

// ---------------- K_A: A[t][r] = sum_v wvu[r][v]*v_seq[t][v] + bu[r] ----------------
__global__ __launch_bounds__(256) void k_a(const float* __restrict__ visible,
                                           const float* __restrict__ wvu,
                                           const float* __restrict__ bu,
                                           float* __restrict__ A) {
  __shared__ float vbuf[NV * 8];
  const int tid = threadIdx.x;
  const int t0 = blockIdx.x * 8;
  for (int idx = tid; idx < NV * 8; idx += 256) {
    int j = idx / NV, v = idx - j * NV;
    int t = t0 + j;
    vbuf[v * 8 + j] = (t < TM1) ? visible[(size_t)(t + 1) * NV + v] : 0.f;
  }
  __syncthreads();
  for (int rr = 0; rr < 2; rr++) {
    int r = tid + rr * 256;
    float b0 = bu[r];
    float acc[8];
#pragma unroll
    for (int j = 0; j < 8; j++) acc[j] = b0;
    const float* wr = wvu + (size_t)r * NV;
    for (int v = 0; v < NV; v++) {
      float wv = wr[v];
#pragma unroll
      for (int j = 0; j < 8; j++) acc[j] = fmaf(wv, vbuf[v * 8 + j], acc[j]);
    }
#pragma unroll
    for (int j = 0; j < 8; j++) {
      int t = t0 + j;
      if (t < TM1) A[(size_t)t * NR + r] = acc[j];
    }
  }
}

// ---------------- K_R: sums of squares for the two Frobenius norms ----------------
__global__ __launch_bounds__(256) void k_r(const float* __restrict__ wuv,
                                           const float* __restrict__ wuh,
                                           float* __restrict__ sc) {
  size_t stride = (size_t)gridDim.x * 256;
  size_t gid = (size_t)blockIdx.x * 256 + threadIdx.x;
  float s1 = 0.f, s2 = 0.f;
  for (size_t i = gid; i < (size_t)NV * NR; i += stride) { float x = wuv[i]; s1 = fmaf(x, x, s1); }
  for (size_t i = gid; i < (size_t)NH * NR; i += stride) { float x = wuh[i]; s2 = fmaf(x, x, s2); }
  for (int off = 32; off > 0; off >>= 1) {
    s1 += __shfl_down(s1, off, 64);
    s2 += __shfl_down(s2, off, 64);
  }
  if ((threadIdx.x & 63) == 0) {
    atomicAdd(&sc[1], s1);
    atomicAdd(&sc[2], s2);
  }
}

// ---------------- K_U v6: 8 co-XCD blocks x 512 thr, wave-per-chunk, 1 barrier/step --
// Block owns 64 rows (slot*64..+64). Wave w owns one 64-wide k-chunk:
//   wave 0 -> chunk==slot (its own output slice: u values stay in registers,
//   zero communication); waves 1..7 -> the 7 remote chunks, polled straight
//   into registers (lane<->word; producer's single coalesced store makes the
//   whole wave discover together). Each wave stages its chunk through a
//   PRIVATE LDS region (write 64, read back float4 broadcast -- same-wave
//   lgkmcnt ordering, no barrier). Partials are double-buffered on t&1 so the
//   single per-step barrier is sufficient by construction: a remote block can
//   only store U[t+1] after discovering U[t], which is after our wave 0
//   finished reading buffer t&1. Arithmetic (8x64 ascending chunks, ascending
//   fmaf, s = a + p0..p7, tanhf) is bit-identical to the verified kernel.
__global__ __launch_bounds__(512, 2) void k_u6(const float* __restrict__ wuu,
                                               const float* __restrict__ A,
                                               const float* __restrict__ u0,
                                               float* __restrict__ U,
                                               unsigned* __restrict__ ub) {
  __shared__ int s_slot;
  __shared__ int s_fast;
  __shared__ float u_buf[NR];          // 8 private 64-float wave regions
  __shared__ float partials[2 * NR];   // double-buffered [t&1][chunk][row]
  const int tid = threadIdx.x;
  unsigned* claimc = ub + 8;
  unsigned* winner = ub + 16;
  unsigned* hs     = ub + 17;          // 4 rounds x 8 slots
  unsigned* vd     = ub + 49;          // 8 verdicts

  // ---- claim 8 co-XCD blocks (pigeonhole on 64 blocks guarantees a winner) ----
  if (tid == 0) {
    unsigned xcd;
    asm volatile("s_getreg_b32 %0, hwreg(HW_REG_XCC_ID, 0, 4)" : "=s"(xcd));
    xcd &= 7u;
    unsigned c = atomicAdd(&claimc[xcd], 1u);
    int slot = -1;
    if (c < 8u) {
      if (c == 7u) atomicCAS(winner, 0xFFFFFFFFu, xcd);
      unsigned wnr;
      do { wnr = agent_load_u32(winner); } while (wnr == 0xFFFFFFFFu);
      if (wnr == xcd) slot = (int)c;
    }
    s_slot = slot;
  }
  __syncthreads();
  const int slot = s_slot;
  if (slot < 0) return;

  // ---- bounded handshake: prove sc0 (XCD-L2) visibility among the 8 ----
  if (tid == 0) {
    int fast = 1;
    for (int round = 0; round < 4 && fast; ++round) {
      unsigned* hw = hs + round * 8;
      store_sc0((float*)&hw[slot], 0.0f);
      for (int o = 0; o < 8; ++o) {
        if (o == slot) continue;
        int ok = 0;
        for (int it = 0; it < 300; ++it) {
          if (load_sc0(&hw[o]) != 0xFFFFFFFFu) { ok = 1; break; }
        }
        if (!ok) fast = 0;
      }
    }
    // verdict over guaranteed AGENT channel; AND of all verdicts
    __hip_atomic_store(&vd[slot], (unsigned)(fast ? 1 : 0),
                       __ATOMIC_RELAXED, __HIP_MEMORY_SCOPE_AGENT);
    for (int o = 0; o < 8; ++o) {
      unsigned v;
      do { v = agent_load_u32(&vd[o]); } while (v == 0xFFFFFFFFu);
      if (v != 1u) fast = 0;
    }
    s_fast = fast;
  }
  __syncthreads();
  const int fast = s_fast;

  const int lane = tid & 63;
  const int wv   = tid >> 6;                 // wave 0..7
  const int r0   = slot * 64;                // owned rows
  // chunk assignment: wave 0 takes the own chunk; waves 1..7 cover the rest
  const int chunk = (wv == 0) ? slot : ((wv - 1 < slot) ? (wv - 1) : wv);
  float* ubw = u_buf + chunk * 64;           // this wave's private region

  // weights: row r0+lane, columns chunk*64..+64 (64 VGPRs; 256-reg budget)
  float Wreg[64];
  {
    const float* wr = wuu + (size_t)(r0 + lane) * NR + chunk * 64;
#pragma unroll
    for (int i = 0; i < 16; i++) {
      float4 w4 = ((const float4*)wr)[i];
      Wreg[4 * i]     = w4.x;
      Wreg[4 * i + 1] = w4.y;
      Wreg[4 * i + 2] = w4.z;
      Wreg[4 * i + 3] = w4.w;
    }
  }
#pragma unroll
  for (int i = 0; i < 64; i++) asm volatile("" : "+v"(Wreg[i]));

  float val = 0.f, a_cur = 0.f;
  if (wv == 0) {
    agent_store_f32(&U[r0 + lane], u0[r0 + lane]);  // row 0 (never polled)
    a_cur = A[r0 + lane];                            // A row 0, for step t=1
  }

#define KU_STEP(T_, UVAL_) do {                                                  \
    ubw[lane] = (UVAL_);                                                         \
    float acc = 0.f;                                                             \
    _Pragma("unroll")                                                            \
    for (int i = 0; i < 64; i += 4) {                                            \
      float4 uv = *(const float4*)(ubw + i);                                     \
      acc = fmaf(Wreg[i],     uv.x, acc);                                        \
      acc = fmaf(Wreg[i + 1], uv.y, acc);                                        \
      acc = fmaf(Wreg[i + 2], uv.z, acc);                                        \
      acc = fmaf(Wreg[i + 3], uv.w, acc);                                        \
    }                                                                            \
    partials[((T_) & 1) * NR + chunk * 64 + lane] = acc;                         \
    __syncthreads();                                                             \
    if (wv == 0) {                                                               \
      float s = a_cur;                                                           \
      _Pragma("unroll")                                                          \
      for (int kk = 0; kk < 8; kk++) s += partials[((T_) & 1) * NR + kk * 64 + lane]; \
      val = tanhf(s);                                                            \
      if (fast) store_sc0(&U[(size_t)(T_) * NR + r0 + lane], val);               \
      else      agent_store_f32(&U[(size_t)(T_) * NR + r0 + lane], val);         \
      a_cur = A[(size_t)(T_) * NR + r0 + lane];  /* prefetch A[t] for t+1 */     \
    }                                                                            \
  } while (0)

  // t = 1: every wave reads its chunk of u0 directly (no polls)
  {
    float u_val = u0[chunk * 64 + lane];
    KU_STEP(1, u_val);
  }
  // t = 2..4094: wave 0 reuses its registers; waves 1..7 poll U[t-1]
  for (int t = 2; t <= TM1 - 1; t++) {
    float u_val;
    if (wv == 0) {
      u_val = val;
    } else {
      const unsigned* p = (const unsigned*)(U + (size_t)(t - 1) * NR) + chunk * 64 + lane;
      unsigned w = fast ? poll_stag_sc0(p) : poll_stag_sys(p);
      u_val = __uint_as_float(w);
    }
    KU_STEP(t, u_val);
  }
#undef KU_STEP
}

// ---------------- K_BH: bh_t, bv_t and the cross-entropy partial sums ----------------
__global__ __launch_bounds__(256) void k_bh(const float* __restrict__ Uu,
                                            const float* __restrict__ wuh,
                                            const float* __restrict__ wuv,
                                            const float* __restrict__ bh,
                                            const float* __restrict__ bv,
                                            const float* __restrict__ visible,
                                            float* __restrict__ bht,
                                            float* __restrict__ bvt,
                                            float* __restrict__ sc) {
  __shared__ float uT[NR * 20];
  __shared__ float red[256];
  const int tid = threadIdx.x;
  const int t0 = blockIdx.x * 16;
  const int nt = min(16, TM1 - t0);
  for (int idx = tid; idx < 16 * NR; idx += 256) {
    int tt = idx >> 9, k = idx & 511;
    uT[k * 20 + tt] = (tt < nt) ? Uu[(size_t)(t0 + tt) * NR + k] : 0.f;
  }
  __syncthreads();
  const int h1 = tid, h2 = tid + 256;
  const bool hasv = tid < NV;
  float acc1[16], acc2[16], accv[16];
#pragma unroll
  for (int i = 0; i < 16; i++) acc1[i] = acc2[i] = accv[i] = 0.f;
  const float* w1p = wuh + (size_t)h1 * NR;
  const float* w2p = wuh + (size_t)h2 * NR;
  const float* wvp = wuv + (size_t)(hasv ? tid : 0) * NR;
  for (int k = 0; k < NR; k++) {
    float u16[16];
#pragma unroll
    for (int q = 0; q < 4; q++) *(float4*)(u16 + 4 * q) = *(const float4*)(uT + k * 20 + 4 * q);
    float a = w1p[k], b = w2p[k];
    float c = hasv ? wvp[k] : 0.f;
#pragma unroll
    for (int i = 0; i < 16; i++) {
      acc1[i] = fmaf(a, u16[i], acc1[i]);
      acc2[i] = fmaf(b, u16[i], acc2[i]);
      accv[i] = fmaf(c, u16[i], accv[i]);
    }
  }
  float bh1 = bh[h1], bh2 = bh[h2];
#pragma unroll
  for (int i = 0; i < 16; i++) {
    if (i < nt) {
      bht[(size_t)(t0 + i) * NH + h1] = acc1[i] + bh1;
      bht[(size_t)(t0 + i) * NH + h2] = acc2[i] + bh2;
    }
  }
  float ce = 0.f;
  if (hasv) {
    float bvv = bv[tid];
    for (int i = 0; i < nt; i++) {
      float x = accv[i] + bvv;
      bvt[(size_t)(t0 + i) * NV + tid] = x;
      float y = sigmoidf_(x);
      float vs = visible[(size_t)(t0 + i + 1) * NV + tid];
      ce += -vs * logf(EPSV + y) - (1.f - vs) * logf(EPSV + 1.f - y);
    }
  }
  red[tid] = ce;
  __syncthreads();
  for (int s = 128; s > 0; s >>= 1) {
    if (tid < s) red[tid] += red[tid + s];
    __syncthreads();
  }
  if (tid == 0) atomicAdd(&sc[0], red[0]);
}

// ---------------- K_G: 20-step Gibbs chain + mse ----------------
__global__ __launch_bounds__(256) void k_g(const float* __restrict__ w,
                                           const float* __restrict__ visible,
                                           const float* __restrict__ rand_h,
                                           const float* __restrict__ rand_v,
                                           const float* __restrict__ bht,
                                           const float* __restrict__ bvt,
                                           float* __restrict__ out) {
  __shared__ float vlds[NV * 20];   // [v][tt] pad 20
  __shared__ float hlds[NH * 20];   // [h][tt] pad 20
  const int tid = threadIdx.x;
  const int t0 = blockIdx.x * 16;
  const int nt = min(16, TM1 - t0);
  for (int idx = tid; idx < NV * 16; idx += 256) {
    int j = idx / NV, v = idx - j * NV;
    vlds[v * 20 + j] = (j < nt) ? visible[(size_t)(t0 + j + 1) * NV + v] : 0.f;
  }
  for (int idx = tid; idx < NH * 20; idx += 256) hlds[idx] = 0.f;
  __syncthreads();
  const int h1 = tid, h2 = tid + 256;
  const int tg = tid >> 5, vg = tid & 31;
  const int v0 = vg * 4;
  const bool bact = vg < 22;
  for (int k = 0; k < GS; k++) {
    {
      float acc1[16], acc2[16];
#pragma unroll
      for (int i = 0; i < 16; i++) acc1[i] = acc2[i] = 0.f;
      const float* w1p = w + (size_t)h1 * NV;
      const float* w2p = w + (size_t)h2 * NV;
      for (int v = 0; v < NV; v++) {
        float vv[16];
#pragma unroll
        for (int q = 0; q < 4; q++) *(float4*)(vv + 4 * q) = *(const float4*)(vlds + v * 20 + 4 * q);
        float a = w1p[v], b = w2p[v];
#pragma unroll
        for (int i = 0; i < 16; i++) {
          acc1[i] = fmaf(a, vv[i], acc1[i]);
          acc2[i] = fmaf(b, vv[i], acc2[i]);
        }
      }
#pragma unroll
      for (int i = 0; i < 16; i++) {
        if (i < nt) {
          size_t t = (size_t)(t0 + i);
          float x1 = acc1[i] + bht[t * NH + h1];
          float x2 = acc2[i] + bht[t * NH + h2];
          float p1 = sigmoidf_(x1);
          float p2 = sigmoidf_(x2);
          float r1 = rand_h[(t * GS + k) * NH + h1];
          float r2 = rand_h[(t * GS + k) * NH + h2];
          hlds[h1 * 20 + i] = (p1 > r1) ? 1.f : 0.f;
          hlds[h2 * 20 + i] = (p2 > r2) ? 1.f : 0.f;
        }
      }
    }
    __syncthreads();
    if (bact) {
      float acc[2][4];
#pragma unroll
      for (int a = 0; a < 2; a++)
#pragma unroll
        for (int b = 0; b < 4; b++) acc[a][b] = 0.f;
#pragma unroll 4
      for (int h = 0; h < NH; h++) {
        float2 hv = *(const float2*)(hlds + h * 20 + tg * 2);
        float4 w4 = *(const float4*)(w + (size_t)h * NV + v0);
        acc[0][0] = fmaf(hv.x, w4.x, acc[0][0]);
        acc[0][1] = fmaf(hv.x, w4.y, acc[0][1]);
        acc[0][2] = fmaf(hv.x, w4.z, acc[0][2]);
        acc[0][3] = fmaf(hv.x, w4.w, acc[0][3]);
        acc[1][0] = fmaf(hv.y, w4.x, acc[1][0]);
        acc[1][1] = fmaf(hv.y, w4.y, acc[1][1]);
        acc[1][2] = fmaf(hv.y, w4.z, acc[1][2]);
        acc[1][3] = fmaf(hv.y, w4.w, acc[1][3]);
      }
#pragma unroll
      for (int a = 0; a < 2; a++) {
        int tt = tg * 2 + a;
        if (tt < nt) {
          size_t t = (size_t)(t0 + tt);
#pragma unroll
          for (int i = 0; i < 4; i++) {
            int v = v0 + i;
            float x = acc[a][i] + bvt[t * NV + v];
            float p = sigmoidf_(x);
            float r = rand_v[(t * GS + k) * NV + v];
            vlds[v * 20 + tt] = (p > r) ? 1.f : 0.f;
          }
        }
      }
    }
    __syncthreads();
  }
  if (tid < 16 && tid < nt) {
    int tt = tid;
    float s = 0.f;
    for (int v = 0; v < NV; v++) {
      float vs = visible[(size_t)(t0 + tt + 1) * NV + v];
      s += fabsf(vs - vlds[v * 20 + tt]);
    }
    out[1 + t0 + tt] = s / 88.f;
  }
}

// ---------------- K_F: finalize scalars ----------------
__global__ void k_f(const float* __restrict__ sc, float* __restrict__ out) {
  float reg = 0.2f * (sqrtf(sc[1]) + sqrtf(sc[2]));
  out[0] = sc[0] / 4096.f + reg;
  out[4096] = reg;
}

extern "C" void kernel_launch(void* const* d_in, const int* in_sizes, int n_in,
                              void* d_out, int out_size, void* d_ws, size_t ws_size,
                              hipStream_t stream) {
  const float* visible = (const float*)d_in[0];
  const float* rand_h  = (const float*)d_in[1];
  const float* rand_v  = (const float*)d_in[2];
  const float* w       = (const float*)d_in[3];
  const float* wuu     = (const float*)d_in[4];
  const float* wuv     = (const float*)d_in[5];
  const float* wuh     = (const float*)d_in[6];
  const float* wvu     = (const float*)d_in[7];
  const float* bv      = (const float*)d_in[8];
  const float* bh      = (const float*)d_in[9];
  const float* bu      = (const float*)d_in[10];
  const float* u0      = (const float*)d_in[11];
  float* out = (float*)d_out;
  float* ws = (float*)d_ws;

  float* Uarr = ws + U_OFF;
  float* Aarr = ws + AB_OFF;  // A; aliased by bh_t after K_U consumes A
  float* bht  = ws + AB_OFF;
  float* bvt  = ws + BV_OFF;
  float* sc   = ws + SC_OFF;
  unsigned* ub = (unsigned*)sc;

  // poison U (poll-on-data); zero accumulators + claim counts;
  // poison winner/handshake/verdict words (words 16..63)
  hipMemsetAsync(Uarr, 0xFF, (size_t)TM1 * NR * sizeof(float), stream);
  hipMemsetAsync(sc, 0, 64, stream);
  hipMemsetAsync((char*)sc + 64, 0xFF, 192, stream);

  k_a<<<512, 256, 0, stream>>>(visible, wvu, bu, Aarr);
  k_r<<<64, 256, 0, stream>>>(wuv, wuh, sc);
  k_u6<<<64, 512, 0, stream>>>(wuu, Aarr, u0, Uarr, ub);
  k_bh<<<256, 256, 0, stream>>>(Uarr, wuh, wuv, bh, bv, visible, bht, bvt, sc);
  k_g<<<256, 256, 0, stream>>>(w, visible, rand_h, rand_v, bht, bvt, out);
  k_f<<<1, 1, 0, stream>>>(sc, out);
}

// Round 2
// 6118.634 us; speedup vs baseline: 1.1105x; 1.1105x over previous
//
#include <hip/hip_runtime.h>
#include <cstdint>
#include <cstddef>

#define T4096 4096
#define TM1 4095
#define NV 88
#define NH 512
#define NR 512
#define GS 20
#define EPSV 1e-6f

// ws float offsets
#define U_OFF 0                         // 4095*512 floats
#define AB_OFF 2096640                  // A, later aliased by bh_t (4095*512)
#define BV_OFF 4193280                  // bv_t 4095*88
#define SC_OFF 4553640                  // scalars + sync area (see layout below)
// u32 layout at sc: [0..2] accumulators, [8..15] xcd claim counts,
// [16] winner, [17..32] handshake words (4 rounds x 4 slots), [33..36] verdicts

__device__ __forceinline__ unsigned int agent_load_u32(const unsigned int* p) {
  return __hip_atomic_load(p, __ATOMIC_RELAXED, __HIP_MEMORY_SCOPE_AGENT);
}
__device__ __forceinline__ void agent_store_f32(float* p, float v) {
  __hip_atomic_store(p, v, __ATOMIC_RELAXED, __HIP_MEMORY_SCOPE_AGENT);
}
__device__ __forceinline__ float sigmoidf_(float x) {
  return 1.0f / (1.0f + expf(-x));
}

// sc0 = SE-scope: bypasses L1, served by the XCD-shared L2.
__device__ __forceinline__ void store_sc0(float* p, float v) {
  asm volatile("global_store_dword %0, %1, off sc0" :: "v"(p), "v"(v) : "memory");
}
__device__ __forceinline__ unsigned load_sc0(const unsigned* p) {
  unsigned r;
  asm volatile("global_load_dword %0, %1, off sc0\n\ts_waitcnt vmcnt(0)"
               : "=v"(r) : "v"(p) : "memory");
  return r;
}

// Rolling 4-deep pipelined poll: 4 loads always in flight; each check waits
// only the OLDEST load (vmcnt(3)), merges any non-poison hit into the
// accumulator via cndmask, exits as soon as every lane has a value, and
// reissues only the consumed slot. Check period ~ RT/4 instead of a full
// sleep+drain iteration (~500-700cyc) -> discovery quantization shrinks to
// tens of cycles. Values are write-once (poison 0xFFFFFFFF -> tanh output),
// so any non-poison hit is THE value. vmcnt(0) at exit quiesces the in-flight
// loads before the registers are reused.
__device__ __forceinline__ unsigned poll_roll_sc0(const unsigned* p) {
  unsigned rA, r0, r1, r2, r3;
  asm volatile(
    "s_waitcnt vmcnt(0)\n\t"
    "v_mov_b32 %0, -1\n\t"
    "global_load_dword %1, %5, off sc0\n\t"
    "global_load_dword %2, %5, off sc0\n\t"
    "global_load_dword %3, %5, off sc0\n\t"
    "global_load_dword %4, %5, off sc0\n\t"
    "Lr%=:\n\t"
    "s_waitcnt vmcnt(3)\n\t"
    "v_cmp_ne_u32 vcc, -1, %1\n\t"
    "v_cndmask_b32 %0, %0, %1, vcc\n\t"
    "v_cmp_eq_u32 vcc, -1, %0\n\t"
    "s_cbranch_vccz Le%=\n\t"
    "global_load_dword %1, %5, off sc0\n\t"
    "s_waitcnt vmcnt(3)\n\t"
    "v_cmp_ne_u32 vcc, -1, %2\n\t"
    "v_cndmask_b32 %0, %0, %2, vcc\n\t"
    "v_cmp_eq_u32 vcc, -1, %0\n\t"
    "s_cbranch_vccz Le%=\n\t"
    "global_load_dword %2, %5, off sc0\n\t"
    "s_waitcnt vmcnt(3)\n\t"
    "v_cmp_ne_u32 vcc, -1, %3\n\t"
    "v_cndmask_b32 %0, %0, %3, vcc\n\t"
    "v_cmp_eq_u32 vcc, -1, %0\n\t"
    "s_cbranch_vccz Le%=\n\t"
    "global_load_dword %3, %5, off sc0\n\t"
    "s_waitcnt vmcnt(3)\n\t"
    "v_cmp_ne_u32 vcc, -1, %4\n\t"
    "v_cndmask_b32 %0, %0, %4, vcc\n\t"
    "v_cmp_eq_u32 vcc, -1, %0\n\t"
    "s_cbranch_vccz Le%=\n\t"
    "global_load_dword %4, %5, off sc0\n\t"
    "s_branch Lr%=\n\t"
    "Le%=:\n\t"
    "s_waitcnt vmcnt(0)\n\t"
    : "=&v"(rA), "=&v"(r0), "=&v"(r1), "=&v"(r2), "=&v"(r3)
    : "v"(p) : "vcc", "memory");
  return rA;
}
// System-scope variant (sc0 sc1): strongest coherence, always correct.
__device__ __forceinline__ unsigned poll_roll_sys(const unsigned* p) {
  unsigned rA, r0, r1, r2, r3;
  asm volatile(
    "s_waitcnt vmcnt(0)\n\t"
    "v_mov_b32 %0, -1\n\t"
    "global_load_dword %1, %5, off sc0 sc1\n\t"
    "global_load_dword %2, %5, off sc0 sc1\n\t"
    "global_load_dword %3, %5, off sc0 sc1\n\t"
    "global_load_dword %4, %5, off sc0 sc1\n\t"
    "Lq%=:\n\t"
    "s_waitcnt vmcnt(3)\n\t"
    "v_cmp_ne_u32 vcc, -1, %1\n\t"
    "v_cndmask_b32 %0, %0, %1, vcc\n\t"
    "v_cmp_eq_u32 vcc, -1, %0\n\t"
    "s_cbranch_vccz Lf%=\n\t"
    "global_load_dword %1, %5, off sc0 sc1\n\t"
    "s_waitcnt vmcnt(3)\n\t"
    "v_cmp_ne_u32 vcc, -1, %2\n\t"
    "v_cndmask_b32 %0, %0, %2, vcc\n\t"
    "v_cmp_eq_u32 vcc, -1, %0\n\t"
    "s_cbranch_vccz Lf%=\n\t"
    "global_load_dword %2, %5, off sc0 sc1\n\t"
    "s_waitcnt vmcnt(3)\n\t"
    "v_cmp_ne_u32 vcc, -1, %3\n\t"
    "v_cndmask_b32 %0, %0, %3, vcc\n\t"
    "v_cmp_eq_u32 vcc, -1, %0\n\t"
    "s_cbranch_vccz Lf%=\n\t"
    "global_load_dword %3, %5, off sc0 sc1\n\t"
    "s_waitcnt vmcnt(3)\n\t"
    "v_cmp_ne_u32 vcc, -1, %4\n\t"
    "v_cndmask_b32 %0, %0, %4, vcc\n\t"
    "v_cmp_eq_u32 vcc, -1, %0\n\t"
    "s_cbranch_vccz Lf%=\n\t"
    "global_load_dword %4, %5, off sc0 sc1\n\t"
    "s_branch Lq%=\n\t"
    "Lf%=:\n\t"
    "s_waitcnt vmcnt(0)\n\t"
    : "=&v"(rA), "=&v"(r0), "=&v"(r1), "=&v"(r2), "=&v"(r3)
    : "v"(p) : "vcc", "memory");
  return rA;
}

// ---------------- K_A: A[t][r] = sum_v wvu[r][v]*v_seq[t][v] + bu[r] ----------------
__global__ __launch_bounds__(256) void k_a(const float* __restrict__ visible,
                                           const float* __restrict__ wvu,
                                           const float* __restrict__ bu,
                                           float* __restrict__ A) {
  __shared__ float vbuf[NV * 8];
  const int tid = threadIdx.x;
  const int t0 = blockIdx.x * 8;
  for (int idx = tid; idx < NV * 8; idx += 256) {
    int j = idx / NV, v = idx - j * NV;
    int t = t0 + j;
    vbuf[v * 8 + j] = (t < TM1) ? visible[(size_t)(t + 1) * NV + v] : 0.f;
  }
  __syncthreads();
  for (int rr = 0; rr < 2; rr++) {
    int r = tid + rr * 256;
    float b0 = bu[r];
    float acc[8];
#pragma unroll
    for (int j = 0; j < 8; j++) acc[j] = b0;
    const float* wr = wvu + (size_t)r * NV;
    for (int v = 0; v < NV; v++) {
      float wv = wr[v];
#pragma unroll
      for (int j = 0; j < 8; j++) acc[j] = fmaf(wv, vbuf[v * 8 + j], acc[j]);
    }
#pragma unroll
    for (int j = 0; j < 8; j++) {
      int t = t0 + j;
      if (t < TM1) A[(size_t)t * NR + r] = acc[j];
    }
  }
}

// ---------------- K_R: sums of squares for the two Frobenius norms ----------------
__global__ __launch_bounds__(256) void k_r(const float* __restrict__ wuv,
                                           const float* __restrict__ wuh,
                                           float* __restrict__ sc) {
  size_t stride = (size_t)gridDim.x * 256;
  size_t gid = (size_t)blockIdx.x * 256 + threadIdx.x;
  float s1 = 0.f, s2 = 0.f;
  for (size_t i = gid; i < (size_t)NV * NR; i += stride) { float x = wuv[i]; s1 = fmaf(x, x, s1); }
  for (size_t i = gid; i < (size_t)NH * NR; i += stride) { float x = wuh[i]; s2 = fmaf(x, x, s2); }
  for (int off = 32; off > 0; off >>= 1) {
    s1 += __shfl_down(s1, off, 64);
    s2 += __shfl_down(s2, off, 64);
  }
  if ((threadIdx.x & 63) == 0) {
    atomicAdd(&sc[1], s1);
    atomicAdd(&sc[2], s2);
  }
}

// ---------------- K_U v5r: verified v5 structure + rolling pipelined poll ----------
// 64 blocks; XCC_ID claim picks 4 co-XCD candidates; a bounded sc0 handshake
// PROVES mutual visibility (else verdicts, exchanged over the known-good AGENT
// channel, send all 4 into the R3-proven LLC protocol). Rolling 4-deep polling
// and VGPR-pinned weights on both paths. Arithmetic order bit-identical to R1/R3.
__global__ __launch_bounds__(1024, 4) void k_u5(const float* __restrict__ wuu,
                                                const float* __restrict__ A,
                                                const float* __restrict__ u0,
                                                float* __restrict__ U,
                                                unsigned* __restrict__ ub) {
  __shared__ int s_slot;
  __shared__ int s_fast;
  __shared__ float u_lds[NR];
  __shared__ float partials[1024];
  const int tid = threadIdx.x;
  unsigned* claimc = ub + 8;
  unsigned* winner = ub + 16;
  unsigned* hs     = ub + 17;
  unsigned* vd     = ub + 33;

  // ---- claim 4 co-XCD blocks ----
  if (tid == 0) {
    unsigned xcd;
    asm volatile("s_getreg_b32 %0, hwreg(HW_REG_XCC_ID, 0, 4)" : "=s"(xcd));
    xcd &= 7u;
    unsigned c = atomicAdd(&claimc[xcd], 1u);
    int slot = -1;
    if (c < 4u) {
      if (c == 3u) atomicCAS(winner, 0xFFFFFFFFu, xcd);
      unsigned wnr;
      do { wnr = agent_load_u32(winner); } while (wnr == 0xFFFFFFFFu);
      if (wnr == xcd) slot = (int)c;
    }
    s_slot = slot;
  }
  __syncthreads();
  const int slot = s_slot;
  if (slot < 0) return;

  // ---- bounded handshake: prove sc0 (XCD-L2) visibility among the 4 ----
  if (tid == 0) {
    int fast = 1;
    for (int round = 0; round < 4 && fast; ++round) {
      unsigned* hw = hs + round * 4;
      store_sc0((float*)&hw[slot], 0.0f);
      for (int o = 0; o < 4; ++o) {
        if (o == slot) continue;
        int ok = 0;
        for (int it = 0; it < 300; ++it) {
          if (load_sc0(&hw[o]) != 0xFFFFFFFFu) { ok = 1; break; }
        }
        if (!ok) fast = 0;
      }
    }
    // verdict over guaranteed AGENT channel; AND of all verdicts
    __hip_atomic_store(&vd[slot], (unsigned)(fast ? 1 : 0),
                       __ATOMIC_RELAXED, __HIP_MEMORY_SCOPE_AGENT);
    for (int o = 0; o < 4; ++o) {
      unsigned v;
      do { v = agent_load_u32(&vd[o]); } while (v == 0xFFFFFFFFu);
      if (v != 1u) fast = 0;
    }
    s_fast = fast;
  }
  __syncthreads();
  const int fast = s_fast;

  const int r_loc = tid & 127;   // row within this block's 128-row slice
  const int kc = tid >> 7;       // k-chunk 0..7 (64 wide) -- same chunking as R1
  const int r0 = slot * 128;

  float Wreg[64];
  {
    const float* wr = wuu + (size_t)(r0 + r_loc) * NR + kc * 64;
#pragma unroll
    for (int i = 0; i < 16; i++) ((float4*)Wreg)[i] = ((const float4*)wr)[i];
  }
  // pin weights in VGPRs (R3 showed the compiler re-loading them every step)
#pragma unroll
  for (int i = 0; i < 64; i++) asm volatile("" : "+v"(Wreg[i]));

  if (tid < NR) u_lds[tid] = u0[tid];
  if (tid < 128) agent_store_f32(&U[r0 + tid], u0[r0 + tid]);  // row 0 (never polled)
  float a_cur = (tid < 128) ? A[r0 + tid] : 0.f;               // A row 0, for step t=1
  int pword = -1;
  if (tid >= 128 && tid < 512) {
    int p = tid - 128;
    pword = (p < r0) ? p : p + 128;
  }
  __syncthreads();

  for (int t = 1; t <= TM1 - 1; t++) {
    float acc = 0.f;
    const float* uc = u_lds + kc * 64;
#pragma unroll
    for (int i = 0; i < 64; i += 4) {
      float4 uv = *(const float4*)(uc + i);
      acc = fmaf(Wreg[i],     uv.x, acc);
      acc = fmaf(Wreg[i + 1], uv.y, acc);
      acc = fmaf(Wreg[i + 2], uv.z, acc);
      acc = fmaf(Wreg[i + 3], uv.w, acc);
    }
    partials[kc * 128 + r_loc] = acc;
    __syncthreads();
    if (tid < 128) {
      float s = a_cur;
#pragma unroll
      for (int kk = 0; kk < 8; kk++) s += partials[kk * 128 + tid];
      float val = tanhf(s);
      if (fast) store_sc0(&U[(size_t)t * NR + r0 + tid], val);
      else      agent_store_f32(&U[(size_t)t * NR + r0 + tid], val);
      u_lds[r0 + tid] = val;                 // own slice: no self-poll
      a_cur = A[(size_t)t * NR + r0 + tid];  // prefetch A row t (hidden by poll)
    } else if (pword >= 0) {
      const unsigned* p = (const unsigned*)(U + (size_t)t * NR) + pword;
      unsigned w = fast ? poll_roll_sc0(p) : poll_roll_sys(p);
      u_lds[pword] = __uint_as_float(w);
    }
    __syncthreads();
  }
}

// ---------------- K_BH: bh_t, bv_t and the cross-entropy partial sums ----------------
__global__ __launch_bounds__(256) void k_bh(const float* __restrict__ Uu,
                                            const float* __restrict__ wuh,
                                            const float* __restrict__ wuv,
                                            const float* __restrict__ bh,
                                            const float* __restrict__ bv,
                                            const float* __restrict__ visible,
                                            float* __restrict__ bht,
                                            float* __restrict__ bvt,
                                            float* __restrict__ sc) {
  __shared__ float uT[NR * 20];
  __shared__ float red[256];
  const int tid = threadIdx.x;
  const int t0 = blockIdx.x * 16;
  const int nt = min(16, TM1 - t0);
  for (int idx = tid; idx < 16 * NR; idx += 256) {
    int tt = idx >> 9, k = idx & 511;
    uT[k * 20 + tt] = (tt < nt) ? Uu[(size_t)(t0 + tt) * NR + k] : 0.f;
  }
  __syncthreads();
  const int h1 = tid, h2 = tid + 256;
  const bool hasv = tid < NV;
  float acc1[16], acc2[16], accv[16];
#pragma unroll
  for (int i = 0; i < 16; i++) acc1[i] = acc2[i] = accv[i] = 0.f;
  const float* w1p = wuh + (size_t)h1 * NR;
  const float* w2p = wuh + (size_t)h2 * NR;
  const float* wvp = wuv + (size_t)(hasv ? tid : 0) * NR;
  for (int k = 0; k < NR; k++) {
    float u16[16];
#pragma unroll
    for (int q = 0; q < 4; q++) *(float4*)(u16 + 4 * q) = *(const float4*)(uT + k * 20 + 4 * q);
    float a = w1p[k], b = w2p[k];
    float c = hasv ? wvp[k] : 0.f;
#pragma unroll
    for (int i = 0; i < 16; i++) {
      acc1[i] = fmaf(a, u16[i], acc1[i]);
      acc2[i] = fmaf(b, u16[i], acc2[i]);
      accv[i] = fmaf(c, u16[i], accv[i]);
    }
  }
  float bh1 = bh[h1], bh2 = bh[h2];
#pragma unroll
  for (int i = 0; i < 16; i++) {
    if (i < nt) {
      bht[(size_t)(t0 + i) * NH + h1] = acc1[i] + bh1;
      bht[(size_t)(t0 + i) * NH + h2] = acc2[i] + bh2;
    }
  }
  float ce = 0.f;
  if (hasv) {
    float bvv = bv[tid];
    for (int i = 0; i < nt; i++) {
      float x = accv[i] + bvv;
      bvt[(size_t)(t0 + i) * NV + tid] = x;
      float y = sigmoidf_(x);
      float vs = visible[(size_t)(t0 + i + 1) * NV + tid];
      ce += -vs * logf(EPSV + y) - (1.f - vs) * logf(EPSV + 1.f - y);
    }
  }
  red[tid] = ce;
  __syncthreads();
  for (int s = 128; s > 0; s >>= 1) {
    if (tid < s) red[tid] += red[tid + s];
    __syncthreads();
  }
  if (tid == 0) atomicAdd(&sc[0], red[0]);
}

// ---------------- K_G: 20-step Gibbs chain + mse ----------------
__global__ __launch_bounds__(256) void k_g(const float* __restrict__ w,
                                           const float* __restrict__ visible,
                                           const float* __restrict__ rand_h,
                                           const float* __restrict__ rand_v,
                                           const float* __restrict__ bht,
                                           const float* __restrict__ bvt,
                                           float* __restrict__ out) {
  __shared__ float vlds[NV * 20];   // [v][tt] pad 20
  __shared__ float hlds[NH * 20];   // [h][tt] pad 20
  const int tid = threadIdx.x;
  const int t0 = blockIdx.x * 16;
  const int nt = min(16, TM1 - t0);
  for (int idx = tid; idx < NV * 16; idx += 256) {
    int j = idx / NV, v = idx - j * NV;
    vlds[v * 20 + j] = (j < nt) ? visible[(size_t)(t0 + j + 1) * NV + v] : 0.f;
  }
  for (int idx = tid; idx < NH * 20; idx += 256) hlds[idx] = 0.f;
  __syncthreads();
  const int h1 = tid, h2 = tid + 256;
  const int tg = tid >> 5, vg = tid & 31;
  const int v0 = vg * 4;
  const bool bact = vg < 22;
  for (int k = 0; k < GS; k++) {
    {
      float acc1[16], acc2[16];
#pragma unroll
      for (int i = 0; i < 16; i++) acc1[i] = acc2[i] = 0.f;
      const float* w1p = w + (size_t)h1 * NV;
      const float* w2p = w + (size_t)h2 * NV;
      for (int v = 0; v < NV; v++) {
        float vv[16];
#pragma unroll
        for (int q = 0; q < 4; q++) *(float4*)(vv + 4 * q) = *(const float4*)(vlds + v * 20 + 4 * q);
        float a = w1p[v], b = w2p[v];
#pragma unroll
        for (int i = 0; i < 16; i++) {
          acc1[i] = fmaf(a, vv[i], acc1[i]);
          acc2[i] = fmaf(b, vv[i], acc2[i]);
        }
      }
#pragma unroll
      for (int i = 0; i < 16; i++) {
        if (i < nt) {
          size_t t = (size_t)(t0 + i);
          float x1 = acc1[i] + bht[t * NH + h1];
          float x2 = acc2[i] + bht[t * NH + h2];
          float p1 = sigmoidf_(x1);
          float p2 = sigmoidf_(x2);
          float r1 = rand_h[(t * GS + k) * NH + h1];
          float r2 = rand_h[(t * GS + k) * NH + h2];
          hlds[h1 * 20 + i] = (p1 > r1) ? 1.f : 0.f;
          hlds[h2 * 20 + i] = (p2 > r2) ? 1.f : 0.f;
        }
      }
    }
    __syncthreads();
    if (bact) {
      float acc[2][4];
#pragma unroll
      for (int a = 0; a < 2; a++)
#pragma unroll
        for (int b = 0; b < 4; b++) acc[a][b] = 0.f;
#pragma unroll 4
      for (int h = 0; h < NH; h++) {
        float2 hv = *(const float2*)(hlds + h * 20 + tg * 2);
        float4 w4 = *(const float4*)(w + (size_t)h * NV + v0);
        acc[0][0] = fmaf(hv.x, w4.x, acc[0][0]);
        acc[0][1] = fmaf(hv.x, w4.y, acc[0][1]);
        acc[0][2] = fmaf(hv.x, w4.z, acc[0][2]);
        acc[0][3] = fmaf(hv.x, w4.w, acc[0][3]);
        acc[1][0] = fmaf(hv.y, w4.x, acc[1][0]);
        acc[1][1] = fmaf(hv.y, w4.y, acc[1][1]);
        acc[1][2] = fmaf(hv.y, w4.z, acc[1][2]);
        acc[1][3] = fmaf(hv.y, w4.w, acc[1][3]);
      }
#pragma unroll
      for (int a = 0; a < 2; a++) {
        int tt = tg * 2 + a;
        if (tt < nt) {
          size_t t = (size_t)(t0 + tt);
#pragma unroll
          for (int i = 0; i < 4; i++) {
            int v = v0 + i;
            float x = acc[a][i] + bvt[t * NV + v];
            float p = sigmoidf_(x);
            float r = rand_v[(t * GS + k) * NV + v];
            vlds[v * 20 + tt] = (p > r) ? 1.f : 0.f;
          }
        }
      }
    }
    __syncthreads();
  }
  if (tid < 16 && tid < nt) {
    int tt = tid;
    float s = 0.f;
    for (int v = 0; v < NV; v++) {
      float vs = visible[(size_t)(t0 + tt + 1) * NV + v];
      s += fabsf(vs - vlds[v * 20 + tt]);
    }
    out[1 + t0 + tt] = s / 88.f;
  }
}

// ---------------- K_F: finalize scalars ----------------
__global__ void k_f(const float* __restrict__ sc, float* __restrict__ out) {
  float reg = 0.2f * (sqrtf(sc[1]) + sqrtf(sc[2]));
  out[0] = sc[0] / 4096.f + reg;
  out[4096] = reg;
}

extern "C" void kernel_launch(void* const* d_in, const int* in_sizes, int n_in,
                              void* d_out, int out_size, void* d_ws, size_t ws_size,
                              hipStream_t stream) {
  const float* visible = (const float*)d_in[0];
  const float* rand_h  = (const float*)d_in[1];
  const float* rand_v  = (const float*)d_in[2];
  const float* w       = (const float*)d_in[3];
  const float* wuu     = (const float*)d_in[4];
  const float* wuv     = (const float*)d_in[5];
  const float* wuh     = (const float*)d_in[6];
  const float* wvu     = (const float*)d_in[7];
  const float* bv      = (const float*)d_in[8];
  const float* bh      = (const float*)d_in[9];
  const float* bu      = (const float*)d_in[10];
  const float* u0      = (const float*)d_in[11];
  float* out = (float*)d_out;
  float* ws = (float*)d_ws;

  float* Uarr = ws + U_OFF;
  float* Aarr = ws + AB_OFF;  // A; aliased by bh_t after K_U consumes A
  float* bht  = ws + AB_OFF;
  float* bvt  = ws + BV_OFF;
  float* sc   = ws + SC_OFF;
  unsigned* ub = (unsigned*)sc;

  // poison U (poll-on-data); zero accumulators + claim counts;
  // poison winner/handshake/verdict words
  hipMemsetAsync(Uarr, 0xFF, (size_t)TM1 * NR * sizeof(float), stream);
  hipMemsetAsync(sc, 0, 64, stream);
  hipMemsetAsync((char*)sc + 64, 0xFF, 96, stream);

  k_a<<<512, 256, 0, stream>>>(visible, wvu, bu, Aarr);
  k_r<<<64, 256, 0, stream>>>(wuv, wuh, sc);
  k_u5<<<64, 1024, 0, stream>>>(wuu, Aarr, u0, Uarr, ub);
  k_bh<<<256, 256, 0, stream>>>(Uarr, wuh, wuv, bh, bv, visible, bht, bvt, sc);
  k_g<<<256, 256, 0, stream>>>(w, visible, rand_h, rand_v, bht, bvt, out);
  k_f<<<1, 1, 0, stream>>>(sc, out);
}

// Round 3
// 5737.705 us; speedup vs baseline: 1.1842x; 1.0664x over previous
//
#include <hip/hip_runtime.h>
#include <cstdint>
#include <cstddef>

#define T4096 4096
#define TM1 4095
#define NV 88
#define NH 512
#define NR 512
#define GS 20
#define EPSV 1e-6f

// ws float offsets
#define U_OFF 0                         // 4095*512 floats
#define AB_OFF 2096640                  // A, later aliased by bh_t (4095*512)
#define BV_OFF 4193280                  // bv_t 4095*88
#define SC_OFF 4553640                  // scalars + sync area (see layout below)
// u32 layout at sc: [0..2] accumulators, [8..15] xcd claim counts,
// [16] winner, [17..32] handshake words (4 rounds x 4 slots), [33..36] verdicts

__device__ __forceinline__ unsigned int agent_load_u32(const unsigned int* p) {
  return __hip_atomic_load(p, __ATOMIC_RELAXED, __HIP_MEMORY_SCOPE_AGENT);
}
__device__ __forceinline__ void agent_store_f32(float* p, float v) {
  __hip_atomic_store(p, v, __ATOMIC_RELAXED, __HIP_MEMORY_SCOPE_AGENT);
}
__device__ __forceinline__ float sigmoidf_(float x) {
  return 1.0f / (1.0f + expf(-x));
}

// sc0 = SE-scope: bypasses L1, served by the XCD-shared L2.
__device__ __forceinline__ void store_sc0(float* p, float v) {
  asm volatile("global_store_dword %0, %1, off sc0" :: "v"(p), "v"(v) : "memory");
}
__device__ __forceinline__ unsigned load_sc0(const unsigned* p) {
  unsigned r;
  asm volatile("global_load_dword %0, %1, off sc0\n\ts_waitcnt vmcnt(0)"
               : "=v"(r) : "v"(p) : "memory");
  return r;
}

// Rolling 4-deep pipelined poll: 4 loads always in flight; each check waits
// only the OLDEST load (vmcnt(3)), merges any non-poison hit into the
// accumulator via cndmask, exits as soon as every lane has a value, and
// reissues only the consumed slot. Values are write-once (poison 0xFFFFFFFF
// -> tanh output), so any non-poison hit is THE value. vmcnt(0) at exit
// quiesces in-flight loads before the registers are reused.
__device__ __forceinline__ unsigned poll_roll_sc0(const unsigned* p) {
  unsigned rA, r0, r1, r2, r3;
  asm volatile(
    "s_waitcnt vmcnt(0)\n\t"
    "v_mov_b32 %0, -1\n\t"
    "global_load_dword %1, %5, off sc0\n\t"
    "global_load_dword %2, %5, off sc0\n\t"
    "global_load_dword %3, %5, off sc0\n\t"
    "global_load_dword %4, %5, off sc0\n\t"
    "Lr%=:\n\t"
    "s_waitcnt vmcnt(3)\n\t"
    "v_cmp_ne_u32 vcc, -1, %1\n\t"
    "v_cndmask_b32 %0, %0, %1, vcc\n\t"
    "v_cmp_eq_u32 vcc, -1, %0\n\t"
    "s_cbranch_vccz Le%=\n\t"
    "global_load_dword %1, %5, off sc0\n\t"
    "s_waitcnt vmcnt(3)\n\t"
    "v_cmp_ne_u32 vcc, -1, %2\n\t"
    "v_cndmask_b32 %0, %0, %2, vcc\n\t"
    "v_cmp_eq_u32 vcc, -1, %0\n\t"
    "s_cbranch_vccz Le%=\n\t"
    "global_load_dword %2, %5, off sc0\n\t"
    "s_waitcnt vmcnt(3)\n\t"
    "v_cmp_ne_u32 vcc, -1, %3\n\t"
    "v_cndmask_b32 %0, %0, %3, vcc\n\t"
    "v_cmp_eq_u32 vcc, -1, %0\n\t"
    "s_cbranch_vccz Le%=\n\t"
    "global_load_dword %3, %5, off sc0\n\t"
    "s_waitcnt vmcnt(3)\n\t"
    "v_cmp_ne_u32 vcc, -1, %4\n\t"
    "v_cndmask_b32 %0, %0, %4, vcc\n\t"
    "v_cmp_eq_u32 vcc, -1, %0\n\t"
    "s_cbranch_vccz Le%=\n\t"
    "global_load_dword %4, %5, off sc0\n\t"
    "s_branch Lr%=\n\t"
    "Le%=:\n\t"
    "s_waitcnt vmcnt(0)\n\t"
    : "=&v"(rA), "=&v"(r0), "=&v"(r1), "=&v"(r2), "=&v"(r3)
    : "v"(p) : "vcc", "memory");
  return rA;
}
// System-scope variant (sc0 sc1): strongest coherence, always correct.
__device__ __forceinline__ unsigned poll_roll_sys(const unsigned* p) {
  unsigned rA, r0, r1, r2, r3;
  asm volatile(
    "s_waitcnt vmcnt(0)\n\t"
    "v_mov_b32 %0, -1\n\t"
    "global_load_dword %1, %5, off sc0 sc1\n\t"
    "global_load_dword %2, %5, off sc0 sc1\n\t"
    "global_load_dword %3, %5, off sc0 sc1\n\t"
    "global_load_dword %4, %5, off sc0 sc1\n\t"
    "Lq%=:\n\t"
    "s_waitcnt vmcnt(3)\n\t"
    "v_cmp_ne_u32 vcc, -1, %1\n\t"
    "v_cndmask_b32 %0, %0, %1, vcc\n\t"
    "v_cmp_eq_u32 vcc, -1, %0\n\t"
    "s_cbranch_vccz Lf%=\n\t"
    "global_load_dword %1, %5, off sc0 sc1\n\t"
    "s_waitcnt vmcnt(3)\n\t"
    "v_cmp_ne_u32 vcc, -1, %2\n\t"
    "v_cndmask_b32 %0, %0, %2, vcc\n\t"
    "v_cmp_eq_u32 vcc, -1, %0\n\t"
    "s_cbranch_vccz Lf%=\n\t"
    "global_load_dword %2, %5, off sc0 sc1\n\t"
    "s_waitcnt vmcnt(3)\n\t"
    "v_cmp_ne_u32 vcc, -1, %3\n\t"
    "v_cndmask_b32 %0, %0, %3, vcc\n\t"
    "v_cmp_eq_u32 vcc, -1, %0\n\t"
    "s_cbranch_vccz Lf%=\n\t"
    "global_load_dword %3, %5, off sc0 sc1\n\t"
    "s_waitcnt vmcnt(3)\n\t"
    "v_cmp_ne_u32 vcc, -1, %4\n\t"
    "v_cndmask_b32 %0, %0, %4, vcc\n\t"
    "v_cmp_eq_u32 vcc, -1, %0\n\t"
    "s_cbranch_vccz Lf%=\n\t"
    "global_load_dword %4, %5, off sc0 sc1\n\t"
    "s_branch Lq%=\n\t"
    "Lf%=:\n\t"
    "s_waitcnt vmcnt(0)\n\t"
    : "=&v"(rA), "=&v"(r0), "=&v"(r1), "=&v"(r2), "=&v"(r3)
    : "v"(p) : "vcc", "memory");
  return rA;
}

// ---------------- K_A: A[t][r] = sum_v wvu[r][v]*v_seq[t][v] + bu[r] ----------------
__global__ __launch_bounds__(256) void k_a(const float* __restrict__ visible,
                                           const float* __restrict__ wvu,
                                           const float* __restrict__ bu,
                                           float* __restrict__ A) {
  __shared__ float vbuf[NV * 8];
  const int tid = threadIdx.x;
  const int t0 = blockIdx.x * 8;
  for (int idx = tid; idx < NV * 8; idx += 256) {
    int j = idx / NV, v = idx - j * NV;
    int t = t0 + j;
    vbuf[v * 8 + j] = (t < TM1) ? visible[(size_t)(t + 1) * NV + v] : 0.f;
  }
  __syncthreads();
  for (int rr = 0; rr < 2; rr++) {
    int r = tid + rr * 256;
    float b0 = bu[r];
    float acc[8];
#pragma unroll
    for (int j = 0; j < 8; j++) acc[j] = b0;
    const float* wr = wvu + (size_t)r * NV;
    for (int v = 0; v < NV; v++) {
      float wv = wr[v];
#pragma unroll
      for (int j = 0; j < 8; j++) acc[j] = fmaf(wv, vbuf[v * 8 + j], acc[j]);
    }
#pragma unroll
    for (int j = 0; j < 8; j++) {
      int t = t0 + j;
      if (t < TM1) A[(size_t)t * NR + r] = acc[j];
    }
  }
}

// ---------------- K_R: sums of squares for the two Frobenius norms ----------------
__global__ __launch_bounds__(256) void k_r(const float* __restrict__ wuv,
                                           const float* __restrict__ wuh,
                                           float* __restrict__ sc) {
  size_t stride = (size_t)gridDim.x * 256;
  size_t gid = (size_t)blockIdx.x * 256 + threadIdx.x;
  float s1 = 0.f, s2 = 0.f;
  for (size_t i = gid; i < (size_t)NV * NR; i += stride) { float x = wuv[i]; s1 = fmaf(x, x, s1); }
  for (size_t i = gid; i < (size_t)NH * NR; i += stride) { float x = wuh[i]; s2 = fmaf(x, x, s2); }
  for (int off = 32; off > 0; off >>= 1) {
    s1 += __shfl_down(s1, off, 64);
    s2 += __shfl_down(s2, off, 64);
  }
  if ((threadIdx.x & 63) == 0) {
    atomicAdd(&sc[1], s1);
    atomicAdd(&sc[2], s2);
  }
}

// ---------------- K_U v7: v5 comm protocol, matvec re-partitioned 2 rows/thread ----
// 512 threads / 8 waves; wave w == k-chunk w (64 wide). Lane L handles rows
// L and L+64 of the block's 128-row slice, so the wave's u-chunk broadcast
// (16 ds_read_b128) is read ONCE and feeds TWO row accumulators: the per-CU
// LDS broadcast storm halves (256 -> 128 b128/step) and the barrier width
// halves (16 -> 8 waves). Poll assignment (tid 128..511), producer rows
// (tid < 128), reduce order, and each row's single ascending fmaf chain are
// IDENTICAL to the verified v5 -> bit-identical results.
__global__ __launch_bounds__(512, 2) void k_u7(const float* __restrict__ wuu,
                                               const float* __restrict__ A,
                                               const float* __restrict__ u0,
                                               float* __restrict__ U,
                                               unsigned* __restrict__ ub) {
  __shared__ int s_slot;
  __shared__ int s_fast;
  __shared__ float u_lds[NR];
  __shared__ float partials[1024];
  const int tid = threadIdx.x;
  unsigned* claimc = ub + 8;
  unsigned* winner = ub + 16;
  unsigned* hs     = ub + 17;
  unsigned* vd     = ub + 33;

  // ---- claim 4 co-XCD blocks ----
  if (tid == 0) {
    unsigned xcd;
    asm volatile("s_getreg_b32 %0, hwreg(HW_REG_XCC_ID, 0, 4)" : "=s"(xcd));
    xcd &= 7u;
    unsigned c = atomicAdd(&claimc[xcd], 1u);
    int slot = -1;
    if (c < 4u) {
      if (c == 3u) atomicCAS(winner, 0xFFFFFFFFu, xcd);
      unsigned wnr;
      do { wnr = agent_load_u32(winner); } while (wnr == 0xFFFFFFFFu);
      if (wnr == xcd) slot = (int)c;
    }
    s_slot = slot;
  }
  __syncthreads();
  const int slot = s_slot;
  if (slot < 0) return;

  // ---- bounded handshake: prove sc0 (XCD-L2) visibility among the 4 ----
  if (tid == 0) {
    int fast = 1;
    for (int round = 0; round < 4 && fast; ++round) {
      unsigned* hw = hs + round * 4;
      store_sc0((float*)&hw[slot], 0.0f);
      for (int o = 0; o < 4; ++o) {
        if (o == slot) continue;
        int ok = 0;
        for (int it = 0; it < 300; ++it) {
          if (load_sc0(&hw[o]) != 0xFFFFFFFFu) { ok = 1; break; }
        }
        if (!ok) fast = 0;
      }
    }
    // verdict over guaranteed AGENT channel; AND of all verdicts
    __hip_atomic_store(&vd[slot], (unsigned)(fast ? 1 : 0),
                       __ATOMIC_RELAXED, __HIP_MEMORY_SCOPE_AGENT);
    for (int o = 0; o < 4; ++o) {
      unsigned v;
      do { v = agent_load_u32(&vd[o]); } while (v == 0xFFFFFFFFu);
      if (v != 1u) fast = 0;
    }
    s_fast = fast;
  }
  __syncthreads();
  const int fast = s_fast;

  const int lane = tid & 63;     // row L within the wave's pair; also chunk word
  const int kc   = tid >> 6;     // k-chunk 0..7 == wave id
  const int r0   = slot * 128;
  const int rA   = lane;         // local rows L and L+64
  const int rB   = lane + 64;

  // weights for BOTH rows of this lane, columns kc*64..+64 (128 VGPRs)
  float WregA[64], WregB[64];
  {
    const float* wra = wuu + (size_t)(r0 + rA) * NR + kc * 64;
    const float* wrb = wuu + (size_t)(r0 + rB) * NR + kc * 64;
#pragma unroll
    for (int i = 0; i < 16; i++) {
      ((float4*)WregA)[i] = ((const float4*)wra)[i];
      ((float4*)WregB)[i] = ((const float4*)wrb)[i];
    }
  }
  // pin weights in registers (compiler otherwise re-loads every step)
#pragma unroll
  for (int i = 0; i < 64; i++) asm volatile("" : "+v"(WregA[i]));
#pragma unroll
  for (int i = 0; i < 64; i++) asm volatile("" : "+v"(WregB[i]));

  if (tid < NR) u_lds[tid] = u0[tid];
  if (tid < 128) agent_store_f32(&U[r0 + tid], u0[r0 + tid]);  // row 0 (never polled)
  float a_cur = (tid < 128) ? A[r0 + tid] : 0.f;               // A row 0, for step t=1
  int pword = -1;
  if (tid >= 128 && tid < 512) {
    int p = tid - 128;
    pword = (p < r0) ? p : p + 128;
  }
  __syncthreads();

  for (int t = 1; t <= TM1 - 1; t++) {
    float acc0 = 0.f, acc1 = 0.f;
    const float* uc = u_lds + kc * 64;
#pragma unroll
    for (int i = 0; i < 64; i += 4) {
      float4 uv = *(const float4*)(uc + i);
      acc0 = fmaf(WregA[i],     uv.x, acc0);
      acc1 = fmaf(WregB[i],     uv.x, acc1);
      acc0 = fmaf(WregA[i + 1], uv.y, acc0);
      acc1 = fmaf(WregB[i + 1], uv.y, acc1);
      acc0 = fmaf(WregA[i + 2], uv.z, acc0);
      acc1 = fmaf(WregB[i + 2], uv.z, acc1);
      acc0 = fmaf(WregA[i + 3], uv.w, acc0);
      acc1 = fmaf(WregB[i + 3], uv.w, acc1);
    }
    partials[kc * 128 + rA] = acc0;
    partials[kc * 128 + rB] = acc1;
    __syncthreads();
    if (tid < 128) {
      float s = a_cur;
#pragma unroll
      for (int kk = 0; kk < 8; kk++) s += partials[kk * 128 + tid];
      float val = tanhf(s);
      if (fast) store_sc0(&U[(size_t)t * NR + r0 + tid], val);
      else      agent_store_f32(&U[(size_t)t * NR + r0 + tid], val);
      u_lds[r0 + tid] = val;                 // own slice: no self-poll
      a_cur = A[(size_t)t * NR + r0 + tid];  // prefetch A row t (hidden by poll)
    } else if (pword >= 0) {
      const unsigned* p = (const unsigned*)(U + (size_t)t * NR) + pword;
      unsigned w = fast ? poll_roll_sc0(p) : poll_roll_sys(p);
      u_lds[pword] = __uint_as_float(w);
    }
    __syncthreads();
  }
}

// ---------------- K_BH: bh_t, bv_t and the cross-entropy partial sums ----------------
__global__ __launch_bounds__(256) void k_bh(const float* __restrict__ Uu,
                                            const float* __restrict__ wuh,
                                            const float* __restrict__ wuv,
                                            const float* __restrict__ bh,
                                            const float* __restrict__ bv,
                                            const float* __restrict__ visible,
                                            float* __restrict__ bht,
                                            float* __restrict__ bvt,
                                            float* __restrict__ sc) {
  __shared__ float uT[NR * 20];
  __shared__ float red[256];
  const int tid = threadIdx.x;
  const int t0 = blockIdx.x * 16;
  const int nt = min(16, TM1 - t0);
  for (int idx = tid; idx < 16 * NR; idx += 256) {
    int tt = idx >> 9, k = idx & 511;
    uT[k * 20 + tt] = (tt < nt) ? Uu[(size_t)(t0 + tt) * NR + k] : 0.f;
  }
  __syncthreads();
  const int h1 = tid, h2 = tid + 256;
  const bool hasv = tid < NV;
  float acc1[16], acc2[16], accv[16];
#pragma unroll
  for (int i = 0; i < 16; i++) acc1[i] = acc2[i] = accv[i] = 0.f;
  const float* w1p = wuh + (size_t)h1 * NR;
  const float* w2p = wuh + (size_t)h2 * NR;
  const float* wvp = wuv + (size_t)(hasv ? tid : 0) * NR;
  for (int k = 0; k < NR; k++) {
    float u16[16];
#pragma unroll
    for (int q = 0; q < 4; q++) *(float4*)(u16 + 4 * q) = *(const float4*)(uT + k * 20 + 4 * q);
    float a = w1p[k], b = w2p[k];
    float c = hasv ? wvp[k] : 0.f;
#pragma unroll
    for (int i = 0; i < 16; i++) {
      acc1[i] = fmaf(a, u16[i], acc1[i]);
      acc2[i] = fmaf(b, u16[i], acc2[i]);
      accv[i] = fmaf(c, u16[i], accv[i]);
    }
  }
  float bh1 = bh[h1], bh2 = bh[h2];
#pragma unroll
  for (int i = 0; i < 16; i++) {
    if (i < nt) {
      bht[(size_t)(t0 + i) * NH + h1] = acc1[i] + bh1;
      bht[(size_t)(t0 + i) * NH + h2] = acc2[i] + bh2;
    }
  }
  float ce = 0.f;
  if (hasv) {
    float bvv = bv[tid];
    for (int i = 0; i < nt; i++) {
      float x = accv[i] + bvv;
      bvt[(size_t)(t0 + i) * NV + tid] = x;
      float y = sigmoidf_(x);
      float vs = visible[(size_t)(t0 + i + 1) * NV + tid];
      ce += -vs * logf(EPSV + y) - (1.f - vs) * logf(EPSV + 1.f - y);
    }
  }
  red[tid] = ce;
  __syncthreads();
  for (int s = 128; s > 0; s >>= 1) {
    if (tid < s) red[tid] += red[tid + s];
    __syncthreads();
  }
  if (tid == 0) atomicAdd(&sc[0], red[0]);
}

// ---------------- K_G: 20-step Gibbs chain + mse ----------------
__global__ __launch_bounds__(256) void k_g(const float* __restrict__ w,
                                           const float* __restrict__ visible,
                                           const float* __restrict__ rand_h,
                                           const float* __restrict__ rand_v,
                                           const float* __restrict__ bht,
                                           const float* __restrict__ bvt,
                                           float* __restrict__ out) {
  __shared__ float vlds[NV * 20];   // [v][tt] pad 20
  __shared__ float hlds[NH * 20];   // [h][tt] pad 20
  const int tid = threadIdx.x;
  const int t0 = blockIdx.x * 16;
  const int nt = min(16, TM1 - t0);
  for (int idx = tid; idx < NV * 16; idx += 256) {
    int j = idx / NV, v = idx - j * NV;
    vlds[v * 20 + j] = (j < nt) ? visible[(size_t)(t0 + j + 1) * NV + v] : 0.f;
  }
  for (int idx = tid; idx < NH * 20; idx += 256) hlds[idx] = 0.f;
  __syncthreads();
  const int h1 = tid, h2 = tid + 256;
  const int tg = tid >> 5, vg = tid & 31;
  const int v0 = vg * 4;
  const bool bact = vg < 22;
  for (int k = 0; k < GS; k++) {
    {
      float acc1[16], acc2[16];
#pragma unroll
      for (int i = 0; i < 16; i++) acc1[i] = acc2[i] = 0.f;
      const float* w1p = w + (size_t)h1 * NV;
      const float* w2p = w + (size_t)h2 * NV;
      for (int v = 0; v < NV; v++) {
        float vv[16];
#pragma unroll
        for (int q = 0; q < 4; q++) *(float4*)(vv + 4 * q) = *(const float4*)(vlds + v * 20 + 4 * q);
        float a = w1p[v], b = w2p[v];
#pragma unroll
        for (int i = 0; i < 16; i++) {
          acc1[i] = fmaf(a, vv[i], acc1[i]);
          acc2[i] = fmaf(b, vv[i], acc2[i]);
        }
      }
#pragma unroll
      for (int i = 0; i < 16; i++) {
        if (i < nt) {
          size_t t = (size_t)(t0 + i);
          float x1 = acc1[i] + bht[t * NH + h1];
          float x2 = acc2[i] + bht[t * NH + h2];
          float p1 = sigmoidf_(x1);
          float p2 = sigmoidf_(x2);
          float r1 = rand_h[(t * GS + k) * NH + h1];
          float r2 = rand_h[(t * GS + k) * NH + h2];
          hlds[h1 * 20 + i] = (p1 > r1) ? 1.f : 0.f;
          hlds[h2 * 20 + i] = (p2 > r2) ? 1.f : 0.f;
        }
      }
    }
    __syncthreads();
    if (bact) {
      float acc[2][4];
#pragma unroll
      for (int a = 0; a < 2; a++)
#pragma unroll
        for (int b = 0; b < 4; b++) acc[a][b] = 0.f;
#pragma unroll 4
      for (int h = 0; h < NH; h++) {
        float2 hv = *(const float2*)(hlds + h * 20 + tg * 2);
        float4 w4 = *(const float4*)(w + (size_t)h * NV + v0);
        acc[0][0] = fmaf(hv.x, w4.x, acc[0][0]);
        acc[0][1] = fmaf(hv.x, w4.y, acc[0][1]);
        acc[0][2] = fmaf(hv.x, w4.z, acc[0][2]);
        acc[0][3] = fmaf(hv.x, w4.w, acc[0][3]);
        acc[1][0] = fmaf(hv.y, w4.x, acc[1][0]);
        acc[1][1] = fmaf(hv.y, w4.y, acc[1][1]);
        acc[1][2] = fmaf(hv.y, w4.z, acc[1][2]);
        acc[1][3] = fmaf(hv.y, w4.w, acc[1][3]);
      }
#pragma unroll
      for (int a = 0; a < 2; a++) {
        int tt = tg * 2 + a;
        if (tt < nt) {
          size_t t = (size_t)(t0 + tt);
#pragma unroll
          for (int i = 0; i < 4; i++) {
            int v = v0 + i;
            float x = acc[a][i] + bvt[t * NV + v];
            float p = sigmoidf_(x);
            float r = rand_v[(t * GS + k) * NV + v];
            vlds[v * 20 + tt] = (p > r) ? 1.f : 0.f;
          }
        }
      }
    }
    __syncthreads();
  }
  if (tid < 16 && tid < nt) {
    int tt = tid;
    float s = 0.f;
    for (int v = 0; v < NV; v++) {
      float vs = visible[(size_t)(t0 + tt + 1) * NV + v];
      s += fabsf(vs - vlds[v * 20 + tt]);
    }
    out[1 + t0 + tt] = s / 88.f;
  }
}

// ---------------- K_F: finalize scalars ----------------
__global__ void k_f(const float* __restrict__ sc, float* __restrict__ out) {
  float reg = 0.2f * (sqrtf(sc[1]) + sqrtf(sc[2]));
  out[0] = sc[0] / 4096.f + reg;
  out[4096] = reg;
}

extern "C" void kernel_launch(void* const* d_in, const int* in_sizes, int n_in,
                              void* d_out, int out_size, void* d_ws, size_t ws_size,
                              hipStream_t stream) {
  const float* visible = (const float*)d_in[0];
  const float* rand_h  = (const float*)d_in[1];
  const float* rand_v  = (const float*)d_in[2];
  const float* w       = (const float*)d_in[3];
  const float* wuu     = (const float*)d_in[4];
  const float* wuv     = (const float*)d_in[5];
  const float* wuh     = (const float*)d_in[6];
  const float* wvu     = (const float*)d_in[7];
  const float* bv      = (const float*)d_in[8];
  const float* bh      = (const float*)d_in[9];
  const float* bu      = (const float*)d_in[10];
  const float* u0      = (const float*)d_in[11];
  float* out = (float*)d_out;
  float* ws = (float*)d_ws;

  float* Uarr = ws + U_OFF;
  float* Aarr = ws + AB_OFF;  // A; aliased by bh_t after K_U consumes A
  float* bht  = ws + AB_OFF;
  float* bvt  = ws + BV_OFF;
  float* sc   = ws + SC_OFF;
  unsigned* ub = (unsigned*)sc;

  // poison U (poll-on-data); zero accumulators + claim counts;
  // poison winner/handshake/verdict words
  hipMemsetAsync(Uarr, 0xFF, (size_t)TM1 * NR * sizeof(float), stream);
  hipMemsetAsync(sc, 0, 64, stream);
  hipMemsetAsync((char*)sc + 64, 0xFF, 96, stream);

  k_a<<<512, 256, 0, stream>>>(visible, wvu, bu, Aarr);
  k_r<<<64, 256, 0, stream>>>(wuv, wuh, sc);
  k_u7<<<64, 512, 0, stream>>>(wuu, Aarr, u0, Uarr, ub);
  k_bh<<<256, 256, 0, stream>>>(Uarr, wuh, wuv, bh, bv, visible, bht, bvt, sc);
  k_g<<<256, 256, 0, stream>>>(w, visible, rand_h, rand_v, bht, bvt, out);
  k_f<<<1, 1, 0, stream>>>(sc, out);
}

// Round 4
// 5484.772 us; speedup vs baseline: 1.2388x; 1.0461x over previous
//
#include <hip/hip_runtime.h>
#include <cstdint>
#include <cstddef>

#define T4096 4096
#define TM1 4095
#define NV 88
#define NH 512
#define NR 512
#define GS 20
#define EPSV 1e-6f

// ws float offsets
#define U_OFF 0                         // 4095*512 floats
#define AB_OFF 2096640                  // A, later aliased by bh_t (4095*512)
#define BV_OFF 4193280                  // bv_t 4095*88
#define SC_OFF 4553640                  // scalars + sync area (see layout below)
// u32 layout at sc: [0..2] accumulators, [8..15] xcd claim counts,
// [16] winner, [17..32] handshake words (4 rounds x 4 slots), [33..36] verdicts

__device__ __forceinline__ unsigned int agent_load_u32(const unsigned int* p) {
  return __hip_atomic_load(p, __ATOMIC_RELAXED, __HIP_MEMORY_SCOPE_AGENT);
}
__device__ __forceinline__ void agent_store_f32(float* p, float v) {
  __hip_atomic_store(p, v, __ATOMIC_RELAXED, __HIP_MEMORY_SCOPE_AGENT);
}
__device__ __forceinline__ float sigmoidf_(float x) {
  return 1.0f / (1.0f + expf(-x));
}

// sc0 = SE-scope: bypasses L1, served by the XCD-shared L2.
__device__ __forceinline__ void store_sc0(float* p, float v) {
  asm volatile("global_store_dword %0, %1, off sc0" :: "v"(p), "v"(v) : "memory");
}
__device__ __forceinline__ unsigned load_sc0(const unsigned* p) {
  unsigned r;
  asm volatile("global_load_dword %0, %1, off sc0\n\ts_waitcnt vmcnt(0)"
               : "=v"(r) : "v"(p) : "memory");
  return r;
}

// Rolling 4-deep pipelined poll: 4 loads always in flight; each check waits
// only the OLDEST load (vmcnt(3)), merges any non-poison hit into the
// accumulator via cndmask, exits as soon as every lane has a value, and
// reissues only the consumed slot. Values are write-once (poison 0xFFFFFFFF
// -> tanh output), so any non-poison hit is THE value. vmcnt(0) at exit
// quiesces in-flight loads before the registers are reused.
__device__ __forceinline__ unsigned poll_roll_sc0(const unsigned* p) {
  unsigned rA, r0, r1, r2, r3;
  asm volatile(
    "s_waitcnt vmcnt(0)\n\t"
    "v_mov_b32 %0, -1\n\t"
    "global_load_dword %1, %5, off sc0\n\t"
    "global_load_dword %2, %5, off sc0\n\t"
    "global_load_dword %3, %5, off sc0\n\t"
    "global_load_dword %4, %5, off sc0\n\t"
    "Lr%=:\n\t"
    "s_waitcnt vmcnt(3)\n\t"
    "v_cmp_ne_u32 vcc, -1, %1\n\t"
    "v_cndmask_b32 %0, %0, %1, vcc\n\t"
    "v_cmp_eq_u32 vcc, -1, %0\n\t"
    "s_cbranch_vccz Le%=\n\t"
    "global_load_dword %1, %5, off sc0\n\t"
    "s_waitcnt vmcnt(3)\n\t"
    "v_cmp_ne_u32 vcc, -1, %2\n\t"
    "v_cndmask_b32 %0, %0, %2, vcc\n\t"
    "v_cmp_eq_u32 vcc, -1, %0\n\t"
    "s_cbranch_vccz Le%=\n\t"
    "global_load_dword %2, %5, off sc0\n\t"
    "s_waitcnt vmcnt(3)\n\t"
    "v_cmp_ne_u32 vcc, -1, %3\n\t"
    "v_cndmask_b32 %0, %0, %3, vcc\n\t"
    "v_cmp_eq_u32 vcc, -1, %0\n\t"
    "s_cbranch_vccz Le%=\n\t"
    "global_load_dword %3, %5, off sc0\n\t"
    "s_waitcnt vmcnt(3)\n\t"
    "v_cmp_ne_u32 vcc, -1, %4\n\t"
    "v_cndmask_b32 %0, %0, %4, vcc\n\t"
    "v_cmp_eq_u32 vcc, -1, %0\n\t"
    "s_cbranch_vccz Le%=\n\t"
    "global_load_dword %4, %5, off sc0\n\t"
    "s_branch Lr%=\n\t"
    "Le%=:\n\t"
    "s_waitcnt vmcnt(0)\n\t"
    : "=&v"(rA), "=&v"(r0), "=&v"(r1), "=&v"(r2), "=&v"(r3)
    : "v"(p) : "vcc", "memory");
  return rA;
}
// System-scope variant (sc0 sc1): strongest coherence, always correct.
__device__ __forceinline__ unsigned poll_roll_sys(const unsigned* p) {
  unsigned rA, r0, r1, r2, r3;
  asm volatile(
    "s_waitcnt vmcnt(0)\n\t"
    "v_mov_b32 %0, -1\n\t"
    "global_load_dword %1, %5, off sc0 sc1\n\t"
    "global_load_dword %2, %5, off sc0 sc1\n\t"
    "global_load_dword %3, %5, off sc0 sc1\n\t"
    "global_load_dword %4, %5, off sc0 sc1\n\t"
    "Lq%=:\n\t"
    "s_waitcnt vmcnt(3)\n\t"
    "v_cmp_ne_u32 vcc, -1, %1\n\t"
    "v_cndmask_b32 %0, %0, %1, vcc\n\t"
    "v_cmp_eq_u32 vcc, -1, %0\n\t"
    "s_cbranch_vccz Lf%=\n\t"
    "global_load_dword %1, %5, off sc0 sc1\n\t"
    "s_waitcnt vmcnt(3)\n\t"
    "v_cmp_ne_u32 vcc, -1, %2\n\t"
    "v_cndmask_b32 %0, %0, %2, vcc\n\t"
    "v_cmp_eq_u32 vcc, -1, %0\n\t"
    "s_cbranch_vccz Lf%=\n\t"
    "global_load_dword %2, %5, off sc0 sc1\n\t"
    "s_waitcnt vmcnt(3)\n\t"
    "v_cmp_ne_u32 vcc, -1, %3\n\t"
    "v_cndmask_b32 %0, %0, %3, vcc\n\t"
    "v_cmp_eq_u32 vcc, -1, %0\n\t"
    "s_cbranch_vccz Lf%=\n\t"
    "global_load_dword %3, %5, off sc0 sc1\n\t"
    "s_waitcnt vmcnt(3)\n\t"
    "v_cmp_ne_u32 vcc, -1, %4\n\t"
    "v_cndmask_b32 %0, %0, %4, vcc\n\t"
    "v_cmp_eq_u32 vcc, -1, %0\n\t"
    "s_cbranch_vccz Lf%=\n\t"
    "global_load_dword %4, %5, off sc0 sc1\n\t"
    "s_branch Lq%=\n\t"
    "Lf%=:\n\t"
    "s_waitcnt vmcnt(0)\n\t"
    : "=&v"(rA), "=&v"(r0), "=&v"(r1), "=&v"(r2), "=&v"(r3)
    : "v"(p) : "vcc", "memory");
  return rA;
}

// ---------------- K_A: A[t][r] = sum_v wvu[r][v]*v_seq[t][v] + bu[r] ----------------
__global__ __launch_bounds__(256) void k_a(const float* __restrict__ visible,
                                           const float* __restrict__ wvu,
                                           const float* __restrict__ bu,
                                           float* __restrict__ A) {
  __shared__ float vbuf[NV * 8];
  const int tid = threadIdx.x;
  const int t0 = blockIdx.x * 8;
  for (int idx = tid; idx < NV * 8; idx += 256) {
    int j = idx / NV, v = idx - j * NV;
    int t = t0 + j;
    vbuf[v * 8 + j] = (t < TM1) ? visible[(size_t)(t + 1) * NV + v] : 0.f;
  }
  __syncthreads();
  for (int rr = 0; rr < 2; rr++) {
    int r = tid + rr * 256;
    float b0 = bu[r];
    float acc[8];
#pragma unroll
    for (int j = 0; j < 8; j++) acc[j] = b0;
    const float* wr = wvu + (size_t)r * NV;
    for (int v = 0; v < NV; v++) {
      float wv = wr[v];
#pragma unroll
      for (int j = 0; j < 8; j++) acc[j] = fmaf(wv, vbuf[v * 8 + j], acc[j]);
    }
#pragma unroll
    for (int j = 0; j < 8; j++) {
      int t = t0 + j;
      if (t < TM1) A[(size_t)t * NR + r] = acc[j];
    }
  }
}

// ---------------- K_R: sums of squares for the two Frobenius norms ----------------
__global__ __launch_bounds__(256) void k_r(const float* __restrict__ wuv,
                                           const float* __restrict__ wuh,
                                           float* __restrict__ sc) {
  size_t stride = (size_t)gridDim.x * 256;
  size_t gid = (size_t)blockIdx.x * 256 + threadIdx.x;
  float s1 = 0.f, s2 = 0.f;
  for (size_t i = gid; i < (size_t)NV * NR; i += stride) { float x = wuv[i]; s1 = fmaf(x, x, s1); }
  for (size_t i = gid; i < (size_t)NH * NR; i += stride) { float x = wuh[i]; s2 = fmaf(x, x, s2); }
  for (int off = 32; off > 0; off >>= 1) {
    s1 += __shfl_down(s1, off, 64);
    s2 += __shfl_down(s2, off, 64);
  }
  if ((threadIdx.x & 63) == 0) {
    atomicAdd(&sc[1], s1);
    atomicAdd(&sc[2], s2);
  }
}

// ---------------- K_U v8: wave==chunk, poll-to-register, ONE barrier/step ----------
// 4 co-XCD blocks x 512 thr (8 waves). Wave w owns k-chunk w (64 wide) for ALL
// 128 of the block's rows (2 rows/lane, v7's row split). The block's two OWN
// chunks (2*slot, 2*slot+1) are exactly the rows its two reduce waves produce:
// those waves keep their tanh output in a register -- zero communication.
// Remote waves poll their chunk word (lane<->word) straight into a register,
// stage through a PRIVATE 64-float LDS region (write + broadcast read back;
// same-wave lgkmcnt ordering, no barrier -- pattern proven in R1), and matvec
// immediately. Partials double-buffered on t&1 => ONE barrier/step is safe:
// a wave writes partials[par^1] only after passing barrier(t), which the
// reduce wave reaches only after finishing its partials[par] reads.
// Row mapping, ascending fmaf chains, reduce order (a_cur + p0..p7), tanhf:
// all identical to verified v7 -> bit-identical results.
__global__ __launch_bounds__(512, 2) void k_u8(const float* __restrict__ wuu,
                                               const float* __restrict__ A,
                                               const float* __restrict__ u0,
                                               float* __restrict__ U,
                                               unsigned* __restrict__ ub) {
  __shared__ int s_slot;
  __shared__ int s_fast;
  __shared__ float u_buf[NR];          // 8 private 64-float wave regions
  __shared__ float partials[2][1024];  // double-buffered [t&1][chunk][row]
  const int tid = threadIdx.x;
  unsigned* claimc = ub + 8;
  unsigned* winner = ub + 16;
  unsigned* hs     = ub + 17;
  unsigned* vd     = ub + 33;

  // ---- claim 4 co-XCD blocks ----
  if (tid == 0) {
    unsigned xcd;
    asm volatile("s_getreg_b32 %0, hwreg(HW_REG_XCC_ID, 0, 4)" : "=s"(xcd));
    xcd &= 7u;
    unsigned c = atomicAdd(&claimc[xcd], 1u);
    int slot = -1;
    if (c < 4u) {
      if (c == 3u) atomicCAS(winner, 0xFFFFFFFFu, xcd);
      unsigned wnr;
      do { wnr = agent_load_u32(winner); } while (wnr == 0xFFFFFFFFu);
      if (wnr == xcd) slot = (int)c;
    }
    s_slot = slot;
  }
  __syncthreads();
  const int slot = s_slot;
  if (slot < 0) return;

  // ---- bounded handshake: prove sc0 (XCD-L2) visibility among the 4 ----
  if (tid == 0) {
    int fast = 1;
    for (int round = 0; round < 4 && fast; ++round) {
      unsigned* hw = hs + round * 4;
      store_sc0((float*)&hw[slot], 0.0f);
      for (int o = 0; o < 4; ++o) {
        if (o == slot) continue;
        int ok = 0;
        for (int it = 0; it < 300; ++it) {
          if (load_sc0(&hw[o]) != 0xFFFFFFFFu) { ok = 1; break; }
        }
        if (!ok) fast = 0;
      }
    }
    // verdict over guaranteed AGENT channel; AND of all verdicts
    __hip_atomic_store(&vd[slot], (unsigned)(fast ? 1 : 0),
                       __ATOMIC_RELAXED, __HIP_MEMORY_SCOPE_AGENT);
    for (int o = 0; o < 4; ++o) {
      unsigned v;
      do { v = agent_load_u32(&vd[o]); } while (v == 0xFFFFFFFFu);
      if (v != 1u) fast = 0;
    }
    s_fast = fast;
  }
  __syncthreads();
  const int fast = s_fast;

  const int lane = tid & 63;
  const int kc   = tid >> 6;                  // wave id == k-chunk 0..7
  const int r0   = slot * 128;
  const bool is_red = (kc >> 1) == slot;      // own chunks 2*slot, 2*slot+1
  const int s_row = ((kc & 1) << 6) + lane;   // reduce wave's row 0..127
  float* ubw = u_buf + kc * 64;               // this wave's private region

  // weights for BOTH rows of this lane (rA=lane, rB=lane+64), cols kc*64..+64
  float WregA[64], WregB[64];
  {
    const float* wra = wuu + (size_t)(r0 + lane) * NR + kc * 64;
    const float* wrb = wuu + (size_t)(r0 + lane + 64) * NR + kc * 64;
#pragma unroll
    for (int i = 0; i < 16; i++) {
      ((float4*)WregA)[i] = ((const float4*)wra)[i];
      ((float4*)WregB)[i] = ((const float4*)wrb)[i];
    }
  }
  // pin weights in registers (compiler otherwise re-loads every step)
#pragma unroll
  for (int i = 0; i < 64; i++) asm volatile("" : "+v"(WregA[i]));
#pragma unroll
  for (int i = 0; i < 64; i++) asm volatile("" : "+v"(WregB[i]));

  float val = 0.f, a_cur = 0.f;
  if (is_red) {
    agent_store_f32(&U[r0 + s_row], u0[r0 + s_row]);  // row 0 (never polled)
    a_cur = A[r0 + s_row];                            // A row 0, for step t=1
  }
  __syncthreads();

#define KU_STEP(T_, UVAL_) do {                                                \
    ubw[lane] = (UVAL_);                                                       \
    float acc0 = 0.f, acc1 = 0.f;                                              \
    _Pragma("unroll")                                                          \
    for (int i = 0; i < 64; i += 4) {                                          \
      float4 uv = *(const float4*)(ubw + i);                                   \
      acc0 = fmaf(WregA[i],     uv.x, acc0);                                   \
      acc1 = fmaf(WregB[i],     uv.x, acc1);                                   \
      acc0 = fmaf(WregA[i + 1], uv.y, acc0);                                   \
      acc1 = fmaf(WregB[i + 1], uv.y, acc1);                                   \
      acc0 = fmaf(WregA[i + 2], uv.z, acc0);                                   \
      acc1 = fmaf(WregB[i + 2], uv.z, acc1);                                   \
      acc0 = fmaf(WregA[i + 3], uv.w, acc0);                                   \
      acc1 = fmaf(WregB[i + 3], uv.w, acc1);                                   \
    }                                                                          \
    float* pb = partials[(T_) & 1];                                            \
    pb[kc * 128 + lane] = acc0;                                                \
    pb[kc * 128 + lane + 64] = acc1;                                           \
    __syncthreads();                                                           \
    if (is_red) {                                                              \
      float s = a_cur;                                                         \
      _Pragma("unroll")                                                        \
      for (int kk = 0; kk < 8; kk++) s += pb[kk * 128 + s_row];                \
      val = tanhf(s);                                                          \
      if (fast) store_sc0(&U[(size_t)(T_) * NR + r0 + s_row], val);            \
      else      agent_store_f32(&U[(size_t)(T_) * NR + r0 + s_row], val);      \
      a_cur = A[(size_t)(T_) * NR + r0 + s_row];  /* prefetch A[t] for t+1 */  \
    }                                                                          \
  } while (0)

  // t = 1: every wave reads its chunk of u0 directly (no polls)
  KU_STEP(1, u0[kc * 64 + lane]);
  // t = 2..4094: reduce waves reuse their register; remote waves poll U[t-1]
  for (int t = 2; t <= TM1 - 1; t++) {
    float u_val;
    if (is_red) {
      u_val = val;
    } else {
      const unsigned* p = (const unsigned*)(U + (size_t)(t - 1) * NR) + kc * 64 + lane;
      unsigned w = fast ? poll_roll_sc0(p) : poll_roll_sys(p);
      u_val = __uint_as_float(w);
    }
    KU_STEP(t, u_val);
  }
#undef KU_STEP
}

// ---------------- K_BH: bh_t, bv_t and the cross-entropy partial sums ----------------
__global__ __launch_bounds__(256) void k_bh(const float* __restrict__ Uu,
                                            const float* __restrict__ wuh,
                                            const float* __restrict__ wuv,
                                            const float* __restrict__ bh,
                                            const float* __restrict__ bv,
                                            const float* __restrict__ visible,
                                            float* __restrict__ bht,
                                            float* __restrict__ bvt,
                                            float* __restrict__ sc) {
  __shared__ float uT[NR * 20];
  __shared__ float red[256];
  const int tid = threadIdx.x;
  const int t0 = blockIdx.x * 16;
  const int nt = min(16, TM1 - t0);
  for (int idx = tid; idx < 16 * NR; idx += 256) {
    int tt = idx >> 9, k = idx & 511;
    uT[k * 20 + tt] = (tt < nt) ? Uu[(size_t)(t0 + tt) * NR + k] : 0.f;
  }
  __syncthreads();
  const int h1 = tid, h2 = tid + 256;
  const bool hasv = tid < NV;
  float acc1[16], acc2[16], accv[16];
#pragma unroll
  for (int i = 0; i < 16; i++) acc1[i] = acc2[i] = accv[i] = 0.f;
  const float* w1p = wuh + (size_t)h1 * NR;
  const float* w2p = wuh + (size_t)h2 * NR;
  const float* wvp = wuv + (size_t)(hasv ? tid : 0) * NR;
  for (int k = 0; k < NR; k++) {
    float u16[16];
#pragma unroll
    for (int q = 0; q < 4; q++) *(float4*)(u16 + 4 * q) = *(const float4*)(uT + k * 20 + 4 * q);
    float a = w1p[k], b = w2p[k];
    float c = hasv ? wvp[k] : 0.f;
#pragma unroll
    for (int i = 0; i < 16; i++) {
      acc1[i] = fmaf(a, u16[i], acc1[i]);
      acc2[i] = fmaf(b, u16[i], acc2[i]);
      accv[i] = fmaf(c, u16[i], accv[i]);
    }
  }
  float bh1 = bh[h1], bh2 = bh[h2];
#pragma unroll
  for (int i = 0; i < 16; i++) {
    if (i < nt) {
      bht[(size_t)(t0 + i) * NH + h1] = acc1[i] + bh1;
      bht[(size_t)(t0 + i) * NH + h2] = acc2[i] + bh2;
    }
  }
  float ce = 0.f;
  if (hasv) {
    float bvv = bv[tid];
    for (int i = 0; i < nt; i++) {
      float x = accv[i] + bvv;
      bvt[(size_t)(t0 + i) * NV + tid] = x;
      float y = sigmoidf_(x);
      float vs = visible[(size_t)(t0 + i + 1) * NV + tid];
      ce += -vs * logf(EPSV + y) - (1.f - vs) * logf(EPSV + 1.f - y);
    }
  }
  red[tid] = ce;
  __syncthreads();
  for (int s = 128; s > 0; s >>= 1) {
    if (tid < s) red[tid] += red[tid + s];
    __syncthreads();
  }
  if (tid == 0) atomicAdd(&sc[0], red[0]);
}

// ---------------- K_G: 20-step Gibbs chain + mse ----------------
__global__ __launch_bounds__(256) void k_g(const float* __restrict__ w,
                                           const float* __restrict__ visible,
                                           const float* __restrict__ rand_h,
                                           const float* __restrict__ rand_v,
                                           const float* __restrict__ bht,
                                           const float* __restrict__ bvt,
                                           float* __restrict__ out) {
  __shared__ float vlds[NV * 20];   // [v][tt] pad 20
  __shared__ float hlds[NH * 20];   // [h][tt] pad 20
  const int tid = threadIdx.x;
  const int t0 = blockIdx.x * 16;
  const int nt = min(16, TM1 - t0);
  for (int idx = tid; idx < NV * 16; idx += 256) {
    int j = idx / NV, v = idx - j * NV;
    vlds[v * 20 + j] = (j < nt) ? visible[(size_t)(t0 + j + 1) * NV + v] : 0.f;
  }
  for (int idx = tid; idx < NH * 20; idx += 256) hlds[idx] = 0.f;
  __syncthreads();
  const int h1 = tid, h2 = tid + 256;
  const int tg = tid >> 5, vg = tid & 31;
  const int v0 = vg * 4;
  const bool bact = vg < 22;
  for (int k = 0; k < GS; k++) {
    {
      float acc1[16], acc2[16];
#pragma unroll
      for (int i = 0; i < 16; i++) acc1[i] = acc2[i] = 0.f;
      const float* w1p = w + (size_t)h1 * NV;
      const float* w2p = w + (size_t)h2 * NV;
      for (int v = 0; v < NV; v++) {
        float vv[16];
#pragma unroll
        for (int q = 0; q < 4; q++) *(float4*)(vv + 4 * q) = *(const float4*)(vlds + v * 20 + 4 * q);
        float a = w1p[v], b = w2p[v];
#pragma unroll
        for (int i = 0; i < 16; i++) {
          acc1[i] = fmaf(a, vv[i], acc1[i]);
          acc2[i] = fmaf(b, vv[i], acc2[i]);
        }
      }
#pragma unroll
      for (int i = 0; i < 16; i++) {
        if (i < nt) {
          size_t t = (size_t)(t0 + i);
          float x1 = acc1[i] + bht[t * NH + h1];
          float x2 = acc2[i] + bht[t * NH + h2];
          float p1 = sigmoidf_(x1);
          float p2 = sigmoidf_(x2);
          float r1 = rand_h[(t * GS + k) * NH + h1];
          float r2 = rand_h[(t * GS + k) * NH + h2];
          hlds[h1 * 20 + i] = (p1 > r1) ? 1.f : 0.f;
          hlds[h2 * 20 + i] = (p2 > r2) ? 1.f : 0.f;
        }
      }
    }
    __syncthreads();
    if (bact) {
      float acc[2][4];
#pragma unroll
      for (int a = 0; a < 2; a++)
#pragma unroll
        for (int b = 0; b < 4; b++) acc[a][b] = 0.f;
#pragma unroll 4
      for (int h = 0; h < NH; h++) {
        float2 hv = *(const float2*)(hlds + h * 20 + tg * 2);
        float4 w4 = *(const float4*)(w + (size_t)h * NV + v0);
        acc[0][0] = fmaf(hv.x, w4.x, acc[0][0]);
        acc[0][1] = fmaf(hv.x, w4.y, acc[0][1]);
        acc[0][2] = fmaf(hv.x, w4.z, acc[0][2]);
        acc[0][3] = fmaf(hv.x, w4.w, acc[0][3]);
        acc[1][0] = fmaf(hv.y, w4.x, acc[1][0]);
        acc[1][1] = fmaf(hv.y, w4.y, acc[1][1]);
        acc[1][2] = fmaf(hv.y, w4.z, acc[1][2]);
        acc[1][3] = fmaf(hv.y, w4.w, acc[1][3]);
      }
#pragma unroll
      for (int a = 0; a < 2; a++) {
        int tt = tg * 2 + a;
        if (tt < nt) {
          size_t t = (size_t)(t0 + tt);
#pragma unroll
          for (int i = 0; i < 4; i++) {
            int v = v0 + i;
            float x = acc[a][i] + bvt[t * NV + v];
            float p = sigmoidf_(x);
            float r = rand_v[(t * GS + k) * NV + v];
            vlds[v * 20 + tt] = (p > r) ? 1.f : 0.f;
          }
        }
      }
    }
    __syncthreads();
  }
  if (tid < 16 && tid < nt) {
    int tt = tid;
    float s = 0.f;
    for (int v = 0; v < NV; v++) {
      float vs = visible[(size_t)(t0 + tt + 1) * NV + v];
      s += fabsf(vs - vlds[v * 20 + tt]);
    }
    out[1 + t0 + tt] = s / 88.f;
  }
}

// ---------------- K_F: finalize scalars ----------------
__global__ void k_f(const float* __restrict__ sc, float* __restrict__ out) {
  float reg = 0.2f * (sqrtf(sc[1]) + sqrtf(sc[2]));
  out[0] = sc[0] / 4096.f + reg;
  out[4096] = reg;
}

extern "C" void kernel_launch(void* const* d_in, const int* in_sizes, int n_in,
                              void* d_out, int out_size, void* d_ws, size_t ws_size,
                              hipStream_t stream) {
  const float* visible = (const float*)d_in[0];
  const float* rand_h  = (const float*)d_in[1];
  const float* rand_v  = (const float*)d_in[2];
  const float* w       = (const float*)d_in[3];
  const float* wuu     = (const float*)d_in[4];
  const float* wuv     = (const float*)d_in[5];
  const float* wuh     = (const float*)d_in[6];
  const float* wvu     = (const float*)d_in[7];
  const float* bv      = (const float*)d_in[8];
  const float* bh      = (const float*)d_in[9];
  const float* bu      = (const float*)d_in[10];
  const float* u0      = (const float*)d_in[11];
  float* out = (float*)d_out;
  float* ws = (float*)d_ws;

  float* Uarr = ws + U_OFF;
  float* Aarr = ws + AB_OFF;  // A; aliased by bh_t after K_U consumes A
  float* bht  = ws + AB_OFF;
  float* bvt  = ws + BV_OFF;
  float* sc   = ws + SC_OFF;
  unsigned* ub = (unsigned*)sc;

  // poison U (poll-on-data); zero accumulators + claim counts;
  // poison winner/handshake/verdict words
  hipMemsetAsync(Uarr, 0xFF, (size_t)TM1 * NR * sizeof(float), stream);
  hipMemsetAsync(sc, 0, 64, stream);
  hipMemsetAsync((char*)sc + 64, 0xFF, 96, stream);

  k_a<<<512, 256, 0, stream>>>(visible, wvu, bu, Aarr);
  k_r<<<64, 256, 0, stream>>>(wuv, wuh, sc);
  k_u8<<<64, 512, 0, stream>>>(wuu, Aarr, u0, Uarr, ub);
  k_bh<<<256, 256, 0, stream>>>(Uarr, wuh, wuv, bh, bv, visible, bht, bvt, sc);
  k_g<<<256, 256, 0, stream>>>(w, visible, rand_h, rand_v, bht, bvt, out);
  k_f<<<1, 1, 0, stream>>>(sc, out);
}